// Round 9
// baseline (2602.982 us; speedup 1.0000x reference)
//
#include <hip/hip_runtime.h>

#define NN 100000
#define NE 1600000
#define HD 128
#define IND 20
#define LNEPS 1e-5f
#define NLIST2 400000   // 4 type regions of NN
#define NBKT 3125       // dst>>5 buckets == k_fused blocks
#define PASSA_B 256     // histogram/scatter blocks
#define EDGES_PER_B 6250
#define WCAT_B 512
#define ENC_B 12500
#define NWIN 8
#define WINB 391        // buckets per scatter window (8*391 >= 3125)
#define ASTRIDE 260     // A-tile row stride in 32-bit words (520 bf16)

typedef unsigned int uint32;
typedef unsigned short ushort16;
typedef __attribute__((ext_vector_type(8))) short bf16x8;
typedef __attribute__((ext_vector_type(4))) float f32x4;
typedef __attribute__((ext_vector_type(2))) float f32x2;

__device__ __forceinline__ ushort16 f2bf(float f) {
    uint32 u = __float_as_uint(f);
    u += 0x7fffu + ((u >> 16) & 1u);   // round-to-nearest-even
    return (ushort16)(u >> 16);
}
__device__ __forceinline__ float bf2f1(ushort16 h) {
    return __uint_as_float(((uint32)h) << 16);
}
__device__ __forceinline__ uint32 pack2bf(float2 v) {
    return (uint32)f2bf(v.x) | ((uint32)f2bf(v.y) << 16);
}

// ---------------- node list: fixed per-type regions ----------------

__global__ __launch_bounds__(256) void k_fill_n(const int* __restrict__ nt,
                                                int* misc, unsigned* nodelist) {
    int i = blockIdx.x * blockDim.x + threadIdx.x;
    int st = gridDim.x * blockDim.x;
    int lane = threadIdx.x & 63;
    for (int n = i; n < NN; n += st) {
        int t = nt[n];
#pragma unroll
        for (int tt = 0; tt < 4; tt++) {
            unsigned long long m = __ballot(t == tt);
            if (t == tt) {
                int leader = __ffsll((unsigned long long)m) - 1;
                int base = 0;
                if (lane == leader) base = atomicAdd(&misc[8 + tt], (int)__popcll(m));
                base = __shfl(base, leader);
                int prefix = (int)__popcll(m & (((unsigned long long)1 << lane) - 1));
                nodelist[tt * NN + base + prefix] = (unsigned)n | ((unsigned)tt << 17);
            }
        }
    }
}

// ---------------- merged: bucket-histogram | weight-pack | encoder ----------------

#define FMA16(A, v0, v1, v2, v3, w)                                       \
    A[0] += v0.x * w; A[1] += v0.y * w; A[2] += v0.z * w; A[3] += v0.w * w; \
    A[4] += v1.x * w; A[5] += v1.y * w; A[6] += v1.z * w; A[7] += v1.w * w; \
    A[8] += v2.x * w; A[9] += v2.y * w; A[10] += v2.z * w; A[11] += v2.w * w; \
    A[12] += v3.x * w; A[13] += v3.y * w; A[14] += v3.z * w; A[15] += v3.w * w;

__global__ __launch_bounds__(256) void k_pre(
        const int* __restrict__ ei, const int* __restrict__ et,
        int* __restrict__ H, ushort16* __restrict__ key16, unsigned* __restrict__ hdr32,
        const unsigned* __restrict__ nodelist, const int* __restrict__ z,
        const float* __restrict__ sd, const float* __restrict__ df,
        const float* __restrict__ cond, const float* __restrict__ mult,
        const float* __restrict__ z_embed,
        const float* __restrict__ W1, const float* __restrict__ b1,
        const float* __restrict__ W2, const float* __restrict__ b2,
        unsigned char* __restrict__ xout,
        const float* __restrict__ rel_W, const float* __restrict__ lin_W,
        ushort16* __restrict__ Wbh, ushort16* __restrict__ Wbl) {
    __shared__ int hist[NBKT];
    __shared__ float raw[32][20];
    __shared__ float h1[128][36];
    __shared__ unsigned ent[32];
    int bid = blockIdx.x;
    int tid = threadIdx.x;

    if (bid < PASSA_B) {
        // ---- pass A: per-block bucket histogram + edge records ----
        for (int k = tid; k < NBKT; k += 256) hist[k] = 0;
        __syncthreads();
        int e0 = bid * EDGES_PER_B;
        int e1 = e0 + EDGES_PER_B;
        for (int e = e0 + tid; e < e1; e += 256) {
            int d = ei[NE + e];
            int s = ei[e];
            int r = et[e];
            int bkt = d >> 5;
            key16[e] = (ushort16)bkt;
            hdr32[e] = (unsigned)s | ((unsigned)r << 17) | ((unsigned)(d & 31) << 19);
            atomicAdd(&hist[bkt], 1);
        }
        __syncthreads();
        for (int k = tid; k < NBKT; k += 256) H[bid * NBKT + k] = hist[k];
        return;
    }
    int j = bid - PASSA_B;
    if (j < WCAT_B) {
        // ---- weights -> bf16 B-fragment hi/lo ----
        int idx = j * 256 + tid;           // exactly 2*512*128
        int jj = idx & 7;
        int lane = (idx >> 3) & 63;
        int ntile = (idx >> 9) & 7;
        int kt = (idx >> 12) & 15;
        int l = (idx >> 16) & 1;
        int k = kt * 32 + ((lane >> 4) * 8) + jj;
        int n = ntile * 16 + (lane & 15);
        float v;
        if (k < 384) v = rel_W[((l * 3 + (k >> 7)) * HD + (k & 127)) * HD + n];
        else         v = lin_W[(l * HD + (k - 384)) * HD + n];
        ushort16 hi = f2bf(v);
        Wbh[idx] = hi;
        Wbl[idx] = f2bf(v - bf2f1(hi));
        return;
    }
    j -= WCAT_B;
    if (j >= ENC_B) return;

    // ---- encoder: 32 same-type nodes per block (early-exit on pad blocks) ----
    int base = j * 32;
    if (tid < 32) ent[tid] = nodelist[base + tid];
    __syncthreads();
    if (ent[0] == 0xFFFFFFFFu) return;
    int type = (int)(ent[0] >> 17);

    for (int idx = tid; idx < 32 * 20; idx += 256) {
        int nl = idx / 20, f = idx - nl * 20;
        unsigned e = ent[nl];
        float v = 0.f;
        if (e != 0xFFFFFFFFu) {
            int node = (int)(e & 0x1FFFF);
            if (f < 16)      v = z_embed[z[node] * 16 + f];
            else if (f == 16) v = sd[node];
            else if (f == 17) v = df[node];
            else if (f == 18) v = cond[node];
            else              v = mult[node];
        }
        raw[nl][f] = v;
    }
    __syncthreads();

    int jf = tid & 127, n0 = (tid >> 7) * 16;
    const float* W1t = W1 + type * IND * HD;
    const float* W2t = W2 + type * HD * HD;

    float acc[16];
#pragma unroll
    for (int i = 0; i < 16; i++) acc[i] = 0.f;
    for (int k = 0; k < IND; k++) {
        float w = W1t[k * HD + jf];
#pragma unroll
        for (int i = 0; i < 16; i++) acc[i] += raw[n0 + i][k] * w;
    }
    float bb = b1[type * HD + jf];
#pragma unroll
    for (int i = 0; i < 16; i++) h1[jf][n0 + i] = fmaxf(acc[i] + bb, 0.f);
    __syncthreads();

#pragma unroll
    for (int i = 0; i < 16; i++) acc[i] = 0.f;
    for (int k = 0; k < HD; k++) {
        float w = W2t[k * HD + jf];
        const float4* hp = (const float4*)&h1[k][n0];
        float4 v0 = hp[0], v1 = hp[1], v2 = hp[2], v3 = hp[3];
        FMA16(acc, v0, v1, v2, v3, w)
    }
    float b2v = b2[type * HD + jf];
#pragma unroll
    for (int i = 0; i < 16; i++) {
        unsigned e = ent[n0 + i];
        if (e != 0xFFFFFFFFu) {
            int node = (int)(e & 0x1FFFF);
            float vv = acc[i] + b2v;
            int pk = __builtin_amdgcn_cvt_pk_fp8_f32(vv, vv, 0, false);
            xout[(size_t)node * HD + jf] = (unsigned char)(pk & 0xff);
        }
    }
}

// ---------------- scans: H column-scan + bucket scan ----------------

__global__ __launch_bounds__(256) void k_s1(int* __restrict__ H, int* __restrict__ btot) {
    int bkt = blockIdx.x * 256 + threadIdx.x;
    if (bkt >= NBKT) return;
    int run = 0;
    for (int jm = 0; jm < PASSA_B; jm += 8) {
        int t0 = H[(jm + 0) * NBKT + bkt];
        int t1 = H[(jm + 1) * NBKT + bkt];
        int t2 = H[(jm + 2) * NBKT + bkt];
        int t3 = H[(jm + 3) * NBKT + bkt];
        int t4 = H[(jm + 4) * NBKT + bkt];
        int t5 = H[(jm + 5) * NBKT + bkt];
        int t6 = H[(jm + 6) * NBKT + bkt];
        int t7 = H[(jm + 7) * NBKT + bkt];
        H[(jm + 0) * NBKT + bkt] = run; run += t0;
        H[(jm + 1) * NBKT + bkt] = run; run += t1;
        H[(jm + 2) * NBKT + bkt] = run; run += t2;
        H[(jm + 3) * NBKT + bkt] = run; run += t3;
        H[(jm + 4) * NBKT + bkt] = run; run += t4;
        H[(jm + 5) * NBKT + bkt] = run; run += t5;
        H[(jm + 6) * NBKT + bkt] = run; run += t6;
        H[(jm + 7) * NBKT + bkt] = run; run += t7;
    }
    btot[bkt] = run;
}

__global__ __launch_bounds__(1024) void k_s2(const int* __restrict__ btot,
                                             int* __restrict__ boff) {
    __shared__ int s[1024];
    int t = threadIdx.x;
    int v4[4];
    int sum = 0;
#pragma unroll
    for (int i = 0; i < 4; i++) {
        int idx = t * 4 + i;
        v4[i] = (idx < NBKT) ? btot[idx] : 0;
        sum += v4[i];
    }
    s[t] = sum;
    __syncthreads();
    for (int o = 1; o < 1024; o <<= 1) {
        int tv = (t >= o) ? s[t - o] : 0;
        __syncthreads();
        s[t] += tv;
        __syncthreads();
    }
    int run = s[t] - sum;
#pragma unroll
    for (int i = 0; i < 4; i++) {
        int idx = t * 4 + i;
        if (idx < NBKT) boff[idx] = run;
        run += v4[i];
    }
    if (t == 1023) boff[NBKT] = NE;
}

// ---------------- windowed atomic-free scatter ----------------

__global__ __launch_bounds__(256) void k_fill(const ushort16* __restrict__ key16,
                                              const unsigned* __restrict__ hdr32,
                                              const int* __restrict__ H,
                                              const int* __restrict__ boff,
                                              unsigned* __restrict__ packed) {
    __shared__ int cur[WINB];
    int blk = blockIdx.x;
    int tid = threadIdx.x;
    int e0 = blk * EDGES_PER_B;
    int e1 = e0 + EDGES_PER_B;
    for (int w = 0; w < NWIN; w++) {
        int lo = w * WINB;
        for (int k = tid; k < WINB; k += 256) {
            int bkt = lo + k;
            cur[k] = (bkt < NBKT) ? (boff[bkt] + H[blk * NBKT + bkt]) : 0;
        }
        __syncthreads();
        for (int e = e0 + tid; e < e1; e += 256) {
            int kb = (int)key16[e];
            unsigned d = (unsigned)(kb - lo);
            if (d < (unsigned)WINB) {
                int p = atomicAdd(&cur[d], 1);
                packed[p] = hdr32[e];
            }
        }
        __syncthreads();
    }
}

// ---------------- fused layer: LDS-atomic agg -> bf16 A-tile -> MFMA -> LN -> fp8 ----------------
// block = 512 thr = 8 waves = 32 dst nodes = bucket blockIdx.x.
// Waves split the bucket's edge list into contiguous chunks; accumulate into
// LDS fp32 acc[32][3][128] via ds_add_f32 (no ordering needed); per-node degree
// counted in LDS; A-tile built in place; MFMA GEMM + LN epilogue as before.

__global__ __launch_bounds__(512) void k_fused(
        const ushort16* __restrict__ x,        // fp8 e4m3, 2 features per ushort, row stride 64
        const unsigned* __restrict__ packed,   // hdr: src|rel<<17|ldst<<19, bucket-sorted
        const int* __restrict__ boff,
        const ushort16* __restrict__ Wbh, const ushort16* __restrict__ Wbl,
        const float* __restrict__ lb, const float* __restrict__ g,
        const float* __restrict__ bta, unsigned char* __restrict__ xout) {
    __shared__ float accs[12288];   // [32 nodes][3 rel][128 feat] fp32; reused as A-tile u32[32][260] and hlds f32[32][132]
    __shared__ int ldeg[32];
    __shared__ float stat[32][2];
    int tid = threadIdx.x;
    int lane = tid & 63;
    int wv = tid >> 6;                     // 0..7
    int b = blockIdx.x;
    int nb = b * 32;

    {
        float4* az = (float4*)accs;
#pragma unroll
        for (int k = 0; k < 6; k++) az[tid + k * 512] = make_float4(0.f, 0.f, 0.f, 0.f);
        if (tid < 32) ldeg[tid] = 0;
    }
    __syncthreads();

    // ---- phase A: LDS-atomic aggregation over this bucket's edges ----
    int s0 = __builtin_amdgcn_readfirstlane(boff[b]);
    int s1 = __builtin_amdgcn_readfirstlane(boff[b + 1]);
    int tot = s1 - s0;
    int chunk = (tot + 7) >> 3;
    int ws = s0 + wv * chunk;
    int we = ws + chunk; if (we > s1) we = s1;
    int lane2 = 2 * lane;

    int e = ws;
    for (; e + 8 <= we; e += 8) {
        unsigned h0 = __builtin_amdgcn_readfirstlane(packed[e]);
        unsigned h1 = __builtin_amdgcn_readfirstlane(packed[e + 1]);
        unsigned h2 = __builtin_amdgcn_readfirstlane(packed[e + 2]);
        unsigned h3 = __builtin_amdgcn_readfirstlane(packed[e + 3]);
        unsigned h4 = __builtin_amdgcn_readfirstlane(packed[e + 4]);
        unsigned h5 = __builtin_amdgcn_readfirstlane(packed[e + 5]);
        unsigned h6 = __builtin_amdgcn_readfirstlane(packed[e + 6]);
        unsigned h7 = __builtin_amdgcn_readfirstlane(packed[e + 7]);
        int u0 = x[(size_t)(h0 & 0x1FFFF) * 64 + lane];
        int u1 = x[(size_t)(h1 & 0x1FFFF) * 64 + lane];
        int u2 = x[(size_t)(h2 & 0x1FFFF) * 64 + lane];
        int u3 = x[(size_t)(h3 & 0x1FFFF) * 64 + lane];
        int u4 = x[(size_t)(h4 & 0x1FFFF) * 64 + lane];
        int u5 = x[(size_t)(h5 & 0x1FFFF) * 64 + lane];
        int u6 = x[(size_t)(h6 & 0x1FFFF) * 64 + lane];
        int u7 = x[(size_t)(h7 & 0x1FFFF) * 64 + lane];
        f32x2 v0 = __builtin_amdgcn_cvt_pk_f32_fp8(u0, false);
        f32x2 v1 = __builtin_amdgcn_cvt_pk_f32_fp8(u1, false);
        f32x2 v2 = __builtin_amdgcn_cvt_pk_f32_fp8(u2, false);
        f32x2 v3 = __builtin_amdgcn_cvt_pk_f32_fp8(u3, false);
        f32x2 v4 = __builtin_amdgcn_cvt_pk_f32_fp8(u4, false);
        f32x2 v5 = __builtin_amdgcn_cvt_pk_f32_fp8(u5, false);
        f32x2 v6 = __builtin_amdgcn_cvt_pk_f32_fp8(u6, false);
        f32x2 v7 = __builtin_amdgcn_cvt_pk_f32_fp8(u7, false);
        int a0 = (int)((((h0 >> 19) * 3 + ((h0 >> 17) & 3)) << 7)) + lane2;
        int a1 = (int)((((h1 >> 19) * 3 + ((h1 >> 17) & 3)) << 7)) + lane2;
        int a2 = (int)((((h2 >> 19) * 3 + ((h2 >> 17) & 3)) << 7)) + lane2;
        int a3 = (int)((((h3 >> 19) * 3 + ((h3 >> 17) & 3)) << 7)) + lane2;
        int a4 = (int)((((h4 >> 19) * 3 + ((h4 >> 17) & 3)) << 7)) + lane2;
        int a5 = (int)((((h5 >> 19) * 3 + ((h5 >> 17) & 3)) << 7)) + lane2;
        int a6 = (int)((((h6 >> 19) * 3 + ((h6 >> 17) & 3)) << 7)) + lane2;
        int a7 = (int)((((h7 >> 19) * 3 + ((h7 >> 17) & 3)) << 7)) + lane2;
        atomicAdd(&accs[a0], v0.x); atomicAdd(&accs[a0 + 1], v0.y);
        atomicAdd(&accs[a1], v1.x); atomicAdd(&accs[a1 + 1], v1.y);
        atomicAdd(&accs[a2], v2.x); atomicAdd(&accs[a2 + 1], v2.y);
        atomicAdd(&accs[a3], v3.x); atomicAdd(&accs[a3 + 1], v3.y);
        atomicAdd(&accs[a4], v4.x); atomicAdd(&accs[a4 + 1], v4.y);
        atomicAdd(&accs[a5], v5.x); atomicAdd(&accs[a5 + 1], v5.y);
        atomicAdd(&accs[a6], v6.x); atomicAdd(&accs[a6 + 1], v6.y);
        atomicAdd(&accs[a7], v7.x); atomicAdd(&accs[a7 + 1], v7.y);
        if (lane < 8) {
            unsigned hh = h0;
            hh = (lane == 1) ? h1 : hh;
            hh = (lane == 2) ? h2 : hh;
            hh = (lane == 3) ? h3 : hh;
            hh = (lane == 4) ? h4 : hh;
            hh = (lane == 5) ? h5 : hh;
            hh = (lane == 6) ? h6 : hh;
            hh = (lane == 7) ? h7 : hh;
            atomicAdd(&ldeg[hh >> 19], 1);
        }
    }
    for (; e < we; e++) {
        unsigned h = __builtin_amdgcn_readfirstlane(packed[e]);
        int u = x[(size_t)(h & 0x1FFFF) * 64 + lane];
        f32x2 v = __builtin_amdgcn_cvt_pk_f32_fp8(u, false);
        int a = (int)((((h >> 19) * 3 + ((h >> 17) & 3)) << 7)) + lane2;
        atomicAdd(&accs[a], v.x); atomicAdd(&accs[a + 1], v.y);
        if (lane == 0) atomicAdd(&ldeg[h >> 19], 1);
    }
    __syncthreads();

    // ---- build bf16 A-tile in place ----
    float2 pan[4][3];
    int selfu[4];
    float idv[4];
#pragma unroll
    for (int i = 0; i < 4; i++) {
        int n = 4 * wv + i;
        selfu[i] = x[(size_t)(nb + n) * 64 + lane];
        const float2* ap = (const float2*)accs;
        pan[i][0] = ap[((n * 3 + 0) << 6) + lane];
        pan[i][1] = ap[((n * 3 + 1) << 6) + lane];
        pan[i][2] = ap[((n * 3 + 2) << 6) + lane];
        int dg = ldeg[n];
        idv[i] = 1.0f / (float)(dg > 0 ? dg : 1);
    }
    __syncthreads();
#pragma unroll
    for (int i = 0; i < 4; i++) {
        int row = 4 * wv + i;
        uint32* ar = (uint32*)accs + row * ASTRIDE;
        float id = idv[i];
        float2 q0 = {pan[i][0].x * id, pan[i][0].y * id};
        float2 q1 = {pan[i][1].x * id, pan[i][1].y * id};
        float2 q2 = {pan[i][2].x * id, pan[i][2].y * id};
        f32x2 vs = __builtin_amdgcn_cvt_pk_f32_fp8(selfu[i], false);
        float2 q3 = {vs.x, vs.y};
        ar[lane]       = pack2bf(q0);
        ar[64 + lane]  = pack2bf(q1);
        ar[128 + lane] = pack2bf(q2);
        ar[192 + lane] = pack2bf(q3);
    }
    __syncthreads();

    // ---- MFMA GEMM (W = Whi + Wlo); wave w: n-tile w, m-tiles {0,1} ----
    uint32* Alds = (uint32*)accs;
    f32x4 acc00 = {0.f, 0.f, 0.f, 0.f}, acc10 = acc00;
    int mrow0 = (lane & 15);
    int mrow1 = 16 + (lane & 15);
    int q4 = (lane >> 4) * 4;
    const bf16x8* wbh = (const bf16x8*)Wbh;
    const bf16x8* wbl = (const bf16x8*)Wbl;

#pragma unroll 4
    for (int kt = 0; kt < 16; kt++) {
        bf16x8 af0 = *(const bf16x8*)&Alds[mrow0 * ASTRIDE + kt * 16 + q4];
        bf16x8 af1 = *(const bf16x8*)&Alds[mrow1 * ASTRIDE + kt * 16 + q4];
        bf16x8 bh0 = wbh[(kt * 8 + wv) * 64 + lane];
        bf16x8 bl0 = wbl[(kt * 8 + wv) * 64 + lane];
        acc00 = __builtin_amdgcn_mfma_f32_16x16x32_bf16(af0, bh0, acc00, 0, 0, 0);
        acc10 = __builtin_amdgcn_mfma_f32_16x16x32_bf16(af1, bh0, acc10, 0, 0, 0);
        acc00 = __builtin_amdgcn_mfma_f32_16x16x32_bf16(af0, bl0, acc00, 0, 0, 0);
        acc10 = __builtin_amdgcn_mfma_f32_16x16x32_bf16(af1, bl0, acc10, 0, 0, 0);
    }
    __syncthreads();   // A-tile reads done; alias as hlds

    // ---- bias into LDS for LN stats ----
    float* hlds = (float*)accs;            // [32][132]
    int n0 = wv * 16 + (lane & 15);
    float bj0 = lb[n0];
    int rbase = (lane >> 4) * 4;
#pragma unroll
    for (int r = 0; r < 4; r++) {
        hlds[(rbase + r) * 132 + n0]      = acc00[r] + bj0;
        hlds[(16 + rbase + r) * 132 + n0] = acc10[r] + bj0;
    }
    __syncthreads();

    {
        int node = tid >> 4, l16 = tid & 15;
        float s = 0.f, ss = 0.f;
#pragma unroll
        for (int i = 0; i < 8; i++) {
            float v = hlds[node * 132 + l16 + 16 * i];
            s += v; ss += v * v;
        }
        for (int d = 8; d >= 1; d >>= 1) {
            s += __shfl_down(s, d, 16);
            ss += __shfl_down(ss, d, 16);
        }
        if (l16 == 0) {
            float mu = s * (1.f / 128.f);
            float var = ss * (1.f / 128.f) - mu * mu;
            stat[node][0] = mu;
            stat[node][1] = rsqrtf(var + LNEPS);
        }
    }
    __syncthreads();

    // ---- LN epilogue + fp8 repack (8B per thread, coalesced) ----
    {
        int node = tid >> 4, q16 = tid & 15;
        float mu = stat[node][0], rs = stat[node][1];
        const float* hr = hlds + node * 132 + q16 * 8;
        int w[2];
#pragma unroll
        for (int p = 0; p < 2; p++) {
            int f = q16 * 8 + p * 4;
            float v0 = (hr[p * 4 + 0] - mu) * rs * g[f + 0] + bta[f + 0];
            float v1 = (hr[p * 4 + 1] - mu) * rs * g[f + 1] + bta[f + 1];
            float v2 = (hr[p * 4 + 2] - mu) * rs * g[f + 2] + bta[f + 2];
            float v3 = (hr[p * 4 + 3] - mu) * rs * g[f + 3] + bta[f + 3];
            int pk = __builtin_amdgcn_cvt_pk_fp8_f32(v0, v1, 0, false);
            pk = __builtin_amdgcn_cvt_pk_fp8_f32(v2, v3, pk, true);
            w[p] = pk;
        }
        *(int2*)(xout + (size_t)(nb + node) * 128 + q16 * 8) = make_int2(w[0], w[1]);
    }
}

// ---------------- pooling + regressor ----------------

__global__ __launch_bounds__(256) void k_pool(const ushort16* __restrict__ x,
                                              const float* regW, const float* reg_b,
                                              float* out) {
    int tid = threadIdx.x;
    int p = tid & 63;
    float sx = 0.f, sy = 0.f;
    int row = blockIdx.x * 4 + (tid >> 6);
    for (; row < NN; row += gridDim.x * 4) {
        int u = x[(size_t)row * 64 + p];
        f32x2 v = __builtin_amdgcn_cvt_pk_f32_fp8(u, false);
        sx += v.x; sy += v.y;
    }
    float s = sx * regW[2 * p] + sy * regW[2 * p + 1];
    for (int d = 32; d >= 1; d >>= 1) s += __shfl_down(s, d);
    __shared__ float red[4];
    if ((tid & 63) == 0) red[tid >> 6] = s;
    __syncthreads();
    if (tid == 0) {
        float t = (red[0] + red[1] + red[2] + red[3]) * (1.0f / (float)NN);
        if (blockIdx.x == 0) t += reg_b[0];
        atomicAdd(out, t);
    }
}

// ---------------- launcher ----------------

extern "C" void kernel_launch(void* const* d_in, const int* in_sizes, int n_in,
                              void* d_out, int out_size, void* d_ws, size_t ws_size,
                              hipStream_t stream) {
    const int*   z       = (const int*)d_in[0];
    const float* sd      = (const float*)d_in[1];
    const float* df      = (const float*)d_in[2];
    const float* cond    = (const float*)d_in[3];
    const float* mult    = (const float*)d_in[4];
    const int*   nt      = (const int*)d_in[5];
    const int*   ei      = (const int*)d_in[6];
    const int*   et      = (const int*)d_in[7];
    const float* z_embed = (const float*)d_in[8];
    const float* enc_W1  = (const float*)d_in[9];
    const float* enc_b1  = (const float*)d_in[10];
    const float* enc_W2  = (const float*)d_in[11];
    const float* enc_b2  = (const float*)d_in[12];
    const float* lin_W   = (const float*)d_in[13];
    const float* lin_b   = (const float*)d_in[14];
    const float* rel_W   = (const float*)d_in[15];
    const float* ln_g    = (const float*)d_in[16];
    const float* ln_b    = (const float*)d_in[17];
    const float* reg_W   = (const float*)d_in[18];
    const float* reg_b   = (const float*)d_in[19];
    float* out = (float*)d_out;

    char* p = (char*)d_ws;
    int* H          = (int*)p;      p += (size_t)PASSA_B * NBKT * 4;   // 3.2 MB
    int* btot       = (int*)p;      p += (size_t)4096 * 4;
    int* boff       = (int*)p;      p += (size_t)4096 * 4;
    int* misc       = (int*)p;      p += 16 * 4;
    ushort16* key16 = (ushort16*)p; p += (size_t)NE * 2;
    unsigned* hdr32 = (unsigned*)p; p += (size_t)NE * 4;
    unsigned* packed   = (unsigned*)p; p += (size_t)NE * 4;
    unsigned* nodelist = (unsigned*)p; p += (size_t)NLIST2 * 4;
    ushort16* Wbh   = (ushort16*)p; p += (size_t)2 * 512 * 128 * 2;
    ushort16* Wbl   = (ushort16*)p; p += (size_t)2 * 512 * 128 * 2;
    unsigned char* x0 = (unsigned char*)p; p += (size_t)NN * HD;
    unsigned char* x1 = (unsigned char*)p; p += (size_t)NN * HD;

    hipMemsetAsync(misc, 0, 64, stream);
    hipMemsetAsync(nodelist, 0xFF, (size_t)NLIST2 * 4, stream);
    hipMemsetAsync(out, 0, 4, stream);

    k_fill_n<<<400, 256, 0, stream>>>(nt, misc, nodelist);
    k_pre<<<PASSA_B + WCAT_B + ENC_B, 256, 0, stream>>>(
        ei, et, H, key16, hdr32,
        nodelist, z, sd, df, cond, mult, z_embed,
        enc_W1, enc_b1, enc_W2, enc_b2, x0,
        rel_W, lin_W, Wbh, Wbl);
    k_s1<<<13, 256, 0, stream>>>(H, btot);
    k_s2<<<1, 1024, 0, stream>>>(btot, boff);
    k_fill<<<PASSA_B, 256, 0, stream>>>(key16, hdr32, H, boff, packed);

    unsigned char* xin = x0; unsigned char* xo = x1;
    for (int l = 0; l < 2; l++) {
        k_fused<<<NBKT, 512, 0, stream>>>((const ushort16*)xin, packed, boff,
                                          Wbh + (size_t)l * 512 * 128,
                                          Wbl + (size_t)l * 512 * 128,
                                          lin_b + l * HD, ln_g + l * HD, ln_b + l * HD,
                                          xo);
        unsigned char* t = xin; xin = xo; xo = t;
    }
    k_pool<<<256, 256, 0, stream>>>((const ushort16*)xin, reg_W, reg_b, out);
}

// Round 10
// 577.330 us; speedup vs baseline: 4.5087x; 4.5087x over previous
//
#include <hip/hip_runtime.h>

#define NN 100000
#define NE 1600000
#define HD 128
#define IND 20
#define LNEPS 1e-5f
#define NLIST2 400000   // 4 type regions of NN
#define NBKT 3125       // dst>>5 buckets == k_fused blocks
#define PASSA_B 256     // histogram/scatter blocks
#define EDGES_PER_B 6250
#define WCAT_B 512
#define ENC_B 12500
#define NWIN 8
#define WINB 391        // buckets per scatter window (8*391 >= 3125)
#define ASTRIDE 260     // A-tile row stride in 32-bit words (520 bf16)
#define SORT_CAP 4096

typedef unsigned int uint32;
typedef unsigned short ushort16;
typedef __attribute__((ext_vector_type(8))) short bf16x8;
typedef __attribute__((ext_vector_type(4))) float f32x4;
typedef __attribute__((ext_vector_type(2))) float f32x2;

__device__ __forceinline__ ushort16 f2bf(float f) {
    uint32 u = __float_as_uint(f);
    u += 0x7fffu + ((u >> 16) & 1u);   // round-to-nearest-even
    return (ushort16)(u >> 16);
}
__device__ __forceinline__ float bf2f1(ushort16 h) {
    return __uint_as_float(((uint32)h) << 16);
}
__device__ __forceinline__ uint32 pack2bf(float2 v) {
    return (uint32)f2bf(v.x) | ((uint32)f2bf(v.y) << 16);
}

// ---------------- node list: fixed per-type regions ----------------

__global__ __launch_bounds__(256) void k_fill_n(const int* __restrict__ nt,
                                                int* misc, unsigned* nodelist) {
    int i = blockIdx.x * blockDim.x + threadIdx.x;
    int st = gridDim.x * blockDim.x;
    int lane = threadIdx.x & 63;
    for (int n = i; n < NN; n += st) {
        int t = nt[n];
#pragma unroll
        for (int tt = 0; tt < 4; tt++) {
            unsigned long long m = __ballot(t == tt);
            if (t == tt) {
                int leader = __ffsll((unsigned long long)m) - 1;
                int base = 0;
                if (lane == leader) base = atomicAdd(&misc[8 + tt], (int)__popcll(m));
                base = __shfl(base, leader);
                int prefix = (int)__popcll(m & (((unsigned long long)1 << lane) - 1));
                nodelist[tt * NN + base + prefix] = (unsigned)n | ((unsigned)tt << 17);
            }
        }
    }
}

// ---------------- merged: bucket-histogram | weight-pack | encoder ----------------

#define FMA16(A, v0, v1, v2, v3, w)                                       \
    A[0] += v0.x * w; A[1] += v0.y * w; A[2] += v0.z * w; A[3] += v0.w * w; \
    A[4] += v1.x * w; A[5] += v1.y * w; A[6] += v1.z * w; A[7] += v1.w * w; \
    A[8] += v2.x * w; A[9] += v2.y * w; A[10] += v2.z * w; A[11] += v2.w * w; \
    A[12] += v3.x * w; A[13] += v3.y * w; A[14] += v3.z * w; A[15] += v3.w * w;

__global__ __launch_bounds__(256) void k_pre(
        const int* __restrict__ ei, const int* __restrict__ et,
        int* __restrict__ H, ushort16* __restrict__ key16, unsigned* __restrict__ hdr32,
        const unsigned* __restrict__ nodelist, const int* __restrict__ z,
        const float* __restrict__ sd, const float* __restrict__ df,
        const float* __restrict__ cond, const float* __restrict__ mult,
        const float* __restrict__ z_embed,
        const float* __restrict__ W1, const float* __restrict__ b1,
        const float* __restrict__ W2, const float* __restrict__ b2,
        unsigned char* __restrict__ xout,
        const float* __restrict__ rel_W, const float* __restrict__ lin_W,
        ushort16* __restrict__ Wbh, ushort16* __restrict__ Wbl) {
    __shared__ int hist[NBKT];
    __shared__ float raw[32][20];
    __shared__ float h1[128][36];
    __shared__ unsigned ent[32];
    int bid = blockIdx.x;
    int tid = threadIdx.x;

    if (bid < PASSA_B) {
        // ---- pass A: per-block bucket histogram + edge records ----
        for (int k = tid; k < NBKT; k += 256) hist[k] = 0;
        __syncthreads();
        int e0 = bid * EDGES_PER_B;
        int e1 = e0 + EDGES_PER_B;
        for (int e = e0 + tid; e < e1; e += 256) {
            int d = ei[NE + e];
            int s = ei[e];
            int r = et[e];
            int bkt = d >> 5;
            key16[e] = (ushort16)bkt;
            hdr32[e] = (unsigned)s | ((unsigned)r << 17) | ((unsigned)(d & 31) << 19);
            atomicAdd(&hist[bkt], 1);
        }
        __syncthreads();
        for (int k = tid; k < NBKT; k += 256) H[bid * NBKT + k] = hist[k];
        return;
    }
    int j = bid - PASSA_B;
    if (j < WCAT_B) {
        // ---- weights -> bf16 B-fragment hi/lo ----
        int idx = j * 256 + tid;           // exactly 2*512*128
        int jj = idx & 7;
        int lane = (idx >> 3) & 63;
        int ntile = (idx >> 9) & 7;
        int kt = (idx >> 12) & 15;
        int l = (idx >> 16) & 1;
        int k = kt * 32 + ((lane >> 4) * 8) + jj;
        int n = ntile * 16 + (lane & 15);
        float v;
        if (k < 384) v = rel_W[((l * 3 + (k >> 7)) * HD + (k & 127)) * HD + n];
        else         v = lin_W[(l * HD + (k - 384)) * HD + n];
        ushort16 hi = f2bf(v);
        Wbh[idx] = hi;
        Wbl[idx] = f2bf(v - bf2f1(hi));
        return;
    }
    j -= WCAT_B;
    if (j >= ENC_B) return;

    // ---- encoder: 32 same-type nodes per block (early-exit on pad blocks) ----
    int base = j * 32;
    if (tid < 32) ent[tid] = nodelist[base + tid];
    __syncthreads();
    if (ent[0] == 0xFFFFFFFFu) return;
    int type = (int)(ent[0] >> 17);

    for (int idx = tid; idx < 32 * 20; idx += 256) {
        int nl = idx / 20, f = idx - nl * 20;
        unsigned e = ent[nl];
        float v = 0.f;
        if (e != 0xFFFFFFFFu) {
            int node = (int)(e & 0x1FFFF);
            if (f < 16)      v = z_embed[z[node] * 16 + f];
            else if (f == 16) v = sd[node];
            else if (f == 17) v = df[node];
            else if (f == 18) v = cond[node];
            else              v = mult[node];
        }
        raw[nl][f] = v;
    }
    __syncthreads();

    int jf = tid & 127, n0 = (tid >> 7) * 16;
    const float* W1t = W1 + type * IND * HD;
    const float* W2t = W2 + type * HD * HD;

    float acc[16];
#pragma unroll
    for (int i = 0; i < 16; i++) acc[i] = 0.f;
    for (int k = 0; k < IND; k++) {
        float w = W1t[k * HD + jf];
#pragma unroll
        for (int i = 0; i < 16; i++) acc[i] += raw[n0 + i][k] * w;
    }
    float bb = b1[type * HD + jf];
#pragma unroll
    for (int i = 0; i < 16; i++) h1[jf][n0 + i] = fmaxf(acc[i] + bb, 0.f);
    __syncthreads();

#pragma unroll
    for (int i = 0; i < 16; i++) acc[i] = 0.f;
    for (int k = 0; k < HD; k++) {
        float w = W2t[k * HD + jf];
        const float4* hp = (const float4*)&h1[k][n0];
        float4 v0 = hp[0], v1 = hp[1], v2 = hp[2], v3 = hp[3];
        FMA16(acc, v0, v1, v2, v3, w)
    }
    float b2v = b2[type * HD + jf];
#pragma unroll
    for (int i = 0; i < 16; i++) {
        unsigned e = ent[n0 + i];
        if (e != 0xFFFFFFFFu) {
            int node = (int)(e & 0x1FFFF);
            float vv = acc[i] + b2v;
            int pk = __builtin_amdgcn_cvt_pk_fp8_f32(vv, vv, 0, false);
            xout[(size_t)node * HD + jf] = (unsigned char)(pk & 0xff);
        }
    }
}

// ---------------- scans: H column-scan + bucket scan ----------------

__global__ __launch_bounds__(256) void k_s1(int* __restrict__ H, int* __restrict__ btot) {
    int bkt = blockIdx.x * 256 + threadIdx.x;
    if (bkt >= NBKT) return;
    int run = 0;
    for (int jm = 0; jm < PASSA_B; jm += 8) {
        int t0 = H[(jm + 0) * NBKT + bkt];
        int t1 = H[(jm + 1) * NBKT + bkt];
        int t2 = H[(jm + 2) * NBKT + bkt];
        int t3 = H[(jm + 3) * NBKT + bkt];
        int t4 = H[(jm + 4) * NBKT + bkt];
        int t5 = H[(jm + 5) * NBKT + bkt];
        int t6 = H[(jm + 6) * NBKT + bkt];
        int t7 = H[(jm + 7) * NBKT + bkt];
        H[(jm + 0) * NBKT + bkt] = run; run += t0;
        H[(jm + 1) * NBKT + bkt] = run; run += t1;
        H[(jm + 2) * NBKT + bkt] = run; run += t2;
        H[(jm + 3) * NBKT + bkt] = run; run += t3;
        H[(jm + 4) * NBKT + bkt] = run; run += t4;
        H[(jm + 5) * NBKT + bkt] = run; run += t5;
        H[(jm + 6) * NBKT + bkt] = run; run += t6;
        H[(jm + 7) * NBKT + bkt] = run; run += t7;
    }
    btot[bkt] = run;
}

__global__ __launch_bounds__(1024) void k_s2(const int* __restrict__ btot,
                                             int* __restrict__ boff) {
    __shared__ int s[1024];
    int t = threadIdx.x;
    int v4[4];
    int sum = 0;
#pragma unroll
    for (int i = 0; i < 4; i++) {
        int idx = t * 4 + i;
        v4[i] = (idx < NBKT) ? btot[idx] : 0;
        sum += v4[i];
    }
    s[t] = sum;
    __syncthreads();
    for (int o = 1; o < 1024; o <<= 1) {
        int tv = (t >= o) ? s[t - o] : 0;
        __syncthreads();
        s[t] += tv;
        __syncthreads();
    }
    int run = s[t] - sum;
#pragma unroll
    for (int i = 0; i < 4; i++) {
        int idx = t * 4 + i;
        if (idx < NBKT) boff[idx] = run;
        run += v4[i];
    }
    if (t == 1023) boff[NBKT] = NE;
}

// ---------------- windowed atomic-free scatter (to bucket granularity) ----------------

__global__ __launch_bounds__(256) void k_fill(const ushort16* __restrict__ key16,
                                              const unsigned* __restrict__ hdr32,
                                              const int* __restrict__ H,
                                              const int* __restrict__ boff,
                                              unsigned* __restrict__ packed) {
    __shared__ int cur[WINB];
    int blk = blockIdx.x;
    int tid = threadIdx.x;
    int e0 = blk * EDGES_PER_B;
    int e1 = e0 + EDGES_PER_B;
    for (int w = 0; w < NWIN; w++) {
        int lo = w * WINB;
        for (int k = tid; k < WINB; k += 256) {
            int bkt = lo + k;
            cur[k] = (bkt < NBKT) ? (boff[bkt] + H[blk * NBKT + bkt]) : 0;
        }
        __syncthreads();
        for (int e = e0 + tid; e < e1; e += 256) {
            int kb = (int)key16[e];
            unsigned d = (unsigned)(kb - lo);
            if (d < (unsigned)WINB) {
                int p = atomicAdd(&cur[d], 1);
                packed[p] = hdr32[e];
            }
        }
        __syncthreads();
    }
}

// ---------------- in-bucket counting sort by (ldst,rel) -> per-(dst,rel) offsets ----------------
// One block per bucket: load ~512 hdr edges to LDS, 96-bin histogram (native
// LDS int atomics), serial scan, scatter src-only back to packed, write off[].

__global__ __launch_bounds__(256) void k_sort2(unsigned* __restrict__ packed,
                                               const int* __restrict__ boff,
                                               int* __restrict__ off) {
    __shared__ unsigned ebuf[SORT_CAP];
    __shared__ int hist[97];
    __shared__ int cur[96];
    int b = blockIdx.x;
    int tid = threadIdx.x;
    int base = boff[b];
    int tot = boff[b + 1] - base;
    if (tot > SORT_CAP) tot = SORT_CAP;   // statistically impossible (mean 512, sigma 23)

    if (tid < 97) hist[tid] = 0;
    for (int e = tid; e < tot; e += 256) ebuf[e] = packed[base + e];
    __syncthreads();
    for (int e = tid; e < tot; e += 256) {
        unsigned h = ebuf[e];
        int key = (int)(h >> 19) * 3 + (int)((h >> 17) & 3);
        atomicAdd(&hist[key], 1);
    }
    __syncthreads();
    if (tid == 0) {
        int run = 0;
        for (int k = 0; k < 96; k++) { int t = hist[k]; hist[k] = run; run += t; }
        hist[96] = run;
    }
    __syncthreads();
    if (tid < 96) {
        cur[tid] = hist[tid];
        off[((b * 32 + tid / 3) << 2) + (tid % 3)] = base + hist[tid];
    }
    if (tid < 32) off[((b * 32 + tid) << 2) + 3] = base + hist[3 * (tid + 1)];
    __syncthreads();
    for (int e = tid; e < tot; e += 256) {
        unsigned h = ebuf[e];
        int key = (int)(h >> 19) * 3 + (int)((h >> 17) & 3);
        int p = atomicAdd(&cur[key], 1);
        packed[base + p] = h & 0x1FFFF;
    }
}

// ---------------- fused layer (round-8 form): register agg -> MFMA -> LN -> fp8 ----------------
// 512 threads = 8 waves; wave w aggregates 4 nodes via a flat clamped 8-wide
// edge loop (8 gathers in flight); relation picked by wave-uniform index
// comparisons against segment boundaries.

#define EDGE_ACC(ek, v)                                                     \
    a0x += ((ek) < bb1) ? (v).x : 0.f; a0y += ((ek) < bb1) ? (v).y : 0.f;   \
    a1x += ((ek) >= bb1 && (ek) < bb2) ? (v).x : 0.f;                       \
    a1y += ((ek) >= bb1 && (ek) < bb2) ? (v).y : 0.f;                       \
    a2x += ((ek) >= bb2 && (ek) < bb3) ? (v).x : 0.f;                       \
    a2y += ((ek) >= bb2 && (ek) < bb3) ? (v).y : 0.f;

__global__ __launch_bounds__(512, 6) void k_fused(
        const ushort16* __restrict__ x,        // fp8 e4m3, 2 features per ushort, row stride 64
        const unsigned* __restrict__ packed,   // src-only, (dst,rel)-sorted
        const int* __restrict__ off,
        const ushort16* __restrict__ Wbh, const ushort16* __restrict__ Wbl,
        const float* __restrict__ lb, const float* __restrict__ g,
        const float* __restrict__ bta, unsigned char* __restrict__ xout) {
    __shared__ uint32 Alds[32 * ASTRIDE];   // bf16 A-tile [32][520]; aliased as hlds [32][132] f32
    __shared__ float stat[32][2];
    int tid = threadIdx.x;
    int lane = tid & 63;
    int wv = tid >> 6;                     // 0..7
    int nb = blockIdx.x * 32;

    // all boundaries for this wave's 4 nodes in one vector load (16 ints used)
    int bv = off[((nb + wv * 4) << 2) + lane];

    // ---- phase A: flat 8-wide clamped edge loop per node ----
#pragma unroll
    for (int i = 0; i < 4; i++) {
        int node = nb + wv * 4 + i;
        int bb0 = __builtin_amdgcn_readlane(bv, 4 * i);
        int bb1 = __builtin_amdgcn_readlane(bv, 4 * i + 1);
        int bb2 = __builtin_amdgcn_readlane(bv, 4 * i + 2);
        int bb3 = __builtin_amdgcn_readlane(bv, 4 * i + 3);
        int deg = bb3 - bb0;
        float id = 1.0f / (float)(deg > 0 ? deg : 1);
        int us = x[(size_t)node * 64 + lane];           // self row (early issue)
        float a0x = 0.f, a0y = 0.f, a1x = 0.f, a1y = 0.f, a2x = 0.f, a2y = 0.f;
        int last = bb3 - 1;
        for (int e = bb0; e < bb3; e += 8) {
            unsigned q0 = packed[e];
            unsigned q1 = packed[e + 1 > last ? last : e + 1];
            unsigned q2 = packed[e + 2 > last ? last : e + 2];
            unsigned q3 = packed[e + 3 > last ? last : e + 3];
            unsigned q4 = packed[e + 4 > last ? last : e + 4];
            unsigned q5 = packed[e + 5 > last ? last : e + 5];
            unsigned q6 = packed[e + 6 > last ? last : e + 6];
            unsigned q7 = packed[e + 7 > last ? last : e + 7];
            int u0 = x[(size_t)q0 * 64 + lane];
            int u1 = x[(size_t)q1 * 64 + lane];
            int u2 = x[(size_t)q2 * 64 + lane];
            int u3 = x[(size_t)q3 * 64 + lane];
            int u4 = x[(size_t)q4 * 64 + lane];
            int u5 = x[(size_t)q5 * 64 + lane];
            int u6 = x[(size_t)q6 * 64 + lane];
            int u7 = x[(size_t)q7 * 64 + lane];
            f32x2 v0 = __builtin_amdgcn_cvt_pk_f32_fp8(u0, false);
            f32x2 v1 = __builtin_amdgcn_cvt_pk_f32_fp8(u1, false);
            f32x2 v2 = __builtin_amdgcn_cvt_pk_f32_fp8(u2, false);
            f32x2 v3 = __builtin_amdgcn_cvt_pk_f32_fp8(u3, false);
            f32x2 v4 = __builtin_amdgcn_cvt_pk_f32_fp8(u4, false);
            f32x2 v5 = __builtin_amdgcn_cvt_pk_f32_fp8(u5, false);
            f32x2 v6 = __builtin_amdgcn_cvt_pk_f32_fp8(u6, false);
            f32x2 v7 = __builtin_amdgcn_cvt_pk_f32_fp8(u7, false);
            EDGE_ACC(e, v0)     EDGE_ACC(e + 1, v1)
            EDGE_ACC(e + 2, v2) EDGE_ACC(e + 3, v3)
            EDGE_ACC(e + 4, v4) EDGE_ACC(e + 5, v5)
            EDGE_ACC(e + 6, v6) EDGE_ACC(e + 7, v7)
        }
        uint32* ar = Alds + (wv * 4 + i) * ASTRIDE;
        float2 s0 = {a0x * id, a0y * id};
        float2 s1 = {a1x * id, a1y * id};
        float2 s2 = {a2x * id, a2y * id};
        f32x2 vs = __builtin_amdgcn_cvt_pk_f32_fp8(us, false);
        float2 s3 = {vs.x, vs.y};
        ar[lane]       = pack2bf(s0);
        ar[64 + lane]  = pack2bf(s1);
        ar[128 + lane] = pack2bf(s2);
        ar[192 + lane] = pack2bf(s3);
    }
    __syncthreads();

    // ---- phase B: MFMA GEMM (W = Whi + Wlo); wave w: n-tile w, m-tiles {0,1} ----
    f32x4 acc00 = {0.f, 0.f, 0.f, 0.f}, acc10 = acc00;
    int mrow0 = (lane & 15);
    int mrow1 = 16 + (lane & 15);
    int q4 = (lane >> 4) * 4;
    const bf16x8* wbh = (const bf16x8*)Wbh;
    const bf16x8* wbl = (const bf16x8*)Wbl;

#pragma unroll 4
    for (int kt = 0; kt < 16; kt++) {
        bf16x8 af0 = *(const bf16x8*)&Alds[mrow0 * ASTRIDE + kt * 16 + q4];
        bf16x8 af1 = *(const bf16x8*)&Alds[mrow1 * ASTRIDE + kt * 16 + q4];
        bf16x8 bh0 = wbh[(kt * 8 + wv) * 64 + lane];
        bf16x8 bl0 = wbl[(kt * 8 + wv) * 64 + lane];
        acc00 = __builtin_amdgcn_mfma_f32_16x16x32_bf16(af0, bh0, acc00, 0, 0, 0);
        acc10 = __builtin_amdgcn_mfma_f32_16x16x32_bf16(af1, bh0, acc10, 0, 0, 0);
        acc00 = __builtin_amdgcn_mfma_f32_16x16x32_bf16(af0, bl0, acc00, 0, 0, 0);
        acc10 = __builtin_amdgcn_mfma_f32_16x16x32_bf16(af1, bl0, acc10, 0, 0, 0);
    }
    __syncthreads();   // A-tile reads done; alias as hlds

    // ---- bias into LDS for LN stats ----
    float* hlds = (float*)Alds;            // [32][132]
    int n0 = wv * 16 + (lane & 15);
    float bj0 = lb[n0];
    int rbase = (lane >> 4) * 4;
#pragma unroll
    for (int r = 0; r < 4; r++) {
        hlds[(rbase + r) * 132 + n0]      = acc00[r] + bj0;
        hlds[(16 + rbase + r) * 132 + n0] = acc10[r] + bj0;
    }
    __syncthreads();

    {
        int node = tid >> 4, l16 = tid & 15;
        float s = 0.f, ss = 0.f;
#pragma unroll
        for (int i = 0; i < 8; i++) {
            float v = hlds[node * 132 + l16 + 16 * i];
            s += v; ss += v * v;
        }
        for (int d = 8; d >= 1; d >>= 1) {
            s += __shfl_down(s, d, 16);
            ss += __shfl_down(ss, d, 16);
        }
        if (l16 == 0) {
            float mu = s * (1.f / 128.f);
            float var = ss * (1.f / 128.f) - mu * mu;
            stat[node][0] = mu;
            stat[node][1] = rsqrtf(var + LNEPS);
        }
    }
    __syncthreads();

    // ---- LN epilogue + fp8 repack (8B per thread, coalesced) ----
    {
        int node = tid >> 4, q16 = tid & 15;
        float mu = stat[node][0], rs = stat[node][1];
        const float* hr = hlds + node * 132 + q16 * 8;
        int w[2];
#pragma unroll
        for (int p = 0; p < 2; p++) {
            int f = q16 * 8 + p * 4;
            float v0 = (hr[p * 4 + 0] - mu) * rs * g[f + 0] + bta[f + 0];
            float v1 = (hr[p * 4 + 1] - mu) * rs * g[f + 1] + bta[f + 1];
            float v2 = (hr[p * 4 + 2] - mu) * rs * g[f + 2] + bta[f + 2];
            float v3 = (hr[p * 4 + 3] - mu) * rs * g[f + 3] + bta[f + 3];
            int pk = __builtin_amdgcn_cvt_pk_fp8_f32(v0, v1, 0, false);
            pk = __builtin_amdgcn_cvt_pk_fp8_f32(v2, v3, pk, true);
            w[p] = pk;
        }
        *(int2*)(xout + (size_t)(nb + node) * 128 + q16 * 8) = make_int2(w[0], w[1]);
    }
}

// ---------------- pooling + regressor ----------------

__global__ __launch_bounds__(256) void k_pool(const ushort16* __restrict__ x,
                                              const float* regW, const float* reg_b,
                                              float* out) {
    int tid = threadIdx.x;
    int p = tid & 63;
    float sx = 0.f, sy = 0.f;
    int row = blockIdx.x * 4 + (tid >> 6);
    for (; row < NN; row += gridDim.x * 4) {
        int u = x[(size_t)row * 64 + p];
        f32x2 v = __builtin_amdgcn_cvt_pk_f32_fp8(u, false);
        sx += v.x; sy += v.y;
    }
    float s = sx * regW[2 * p] + sy * regW[2 * p + 1];
    for (int d = 32; d >= 1; d >>= 1) s += __shfl_down(s, d);
    __shared__ float red[4];
    if ((tid & 63) == 0) red[tid >> 6] = s;
    __syncthreads();
    if (tid == 0) {
        float t = (red[0] + red[1] + red[2] + red[3]) * (1.0f / (float)NN);
        if (blockIdx.x == 0) t += reg_b[0];
        atomicAdd(out, t);
    }
}

// ---------------- launcher ----------------

extern "C" void kernel_launch(void* const* d_in, const int* in_sizes, int n_in,
                              void* d_out, int out_size, void* d_ws, size_t ws_size,
                              hipStream_t stream) {
    const int*   z       = (const int*)d_in[0];
    const float* sd      = (const float*)d_in[1];
    const float* df      = (const float*)d_in[2];
    const float* cond    = (const float*)d_in[3];
    const float* mult    = (const float*)d_in[4];
    const int*   nt      = (const int*)d_in[5];
    const int*   ei      = (const int*)d_in[6];
    const int*   et      = (const int*)d_in[7];
    const float* z_embed = (const float*)d_in[8];
    const float* enc_W1  = (const float*)d_in[9];
    const float* enc_b1  = (const float*)d_in[10];
    const float* enc_W2  = (const float*)d_in[11];
    const float* enc_b2  = (const float*)d_in[12];
    const float* lin_W   = (const float*)d_in[13];
    const float* lin_b   = (const float*)d_in[14];
    const float* rel_W   = (const float*)d_in[15];
    const float* ln_g    = (const float*)d_in[16];
    const float* ln_b    = (const float*)d_in[17];
    const float* reg_W   = (const float*)d_in[18];
    const float* reg_b   = (const float*)d_in[19];
    float* out = (float*)d_out;

    char* p = (char*)d_ws;
    int* H          = (int*)p;      p += (size_t)PASSA_B * NBKT * 4;   // 3.2 MB
    int* btot       = (int*)p;      p += (size_t)4096 * 4;
    int* boff       = (int*)p;      p += (size_t)4096 * 4;
    int* misc       = (int*)p;      p += 16 * 4;
    int* off        = (int*)p;      p += (size_t)400384 * 4;           // 4*NN + readlane pad
    ushort16* key16 = (ushort16*)p; p += (size_t)NE * 2;
    unsigned* hdr32 = (unsigned*)p; p += (size_t)NE * 4;
    unsigned* packed   = (unsigned*)p; p += (size_t)NE * 4;
    unsigned* nodelist = (unsigned*)p; p += (size_t)NLIST2 * 4;
    ushort16* Wbh   = (ushort16*)p; p += (size_t)2 * 512 * 128 * 2;
    ushort16* Wbl   = (ushort16*)p; p += (size_t)2 * 512 * 128 * 2;
    unsigned char* x0 = (unsigned char*)p; p += (size_t)NN * HD;
    unsigned char* x1 = (unsigned char*)p; p += (size_t)NN * HD;

    hipMemsetAsync(misc, 0, 64, stream);
    hipMemsetAsync(nodelist, 0xFF, (size_t)NLIST2 * 4, stream);
    hipMemsetAsync(out, 0, 4, stream);

    k_fill_n<<<400, 256, 0, stream>>>(nt, misc, nodelist);
    k_pre<<<PASSA_B + WCAT_B + ENC_B, 256, 0, stream>>>(
        ei, et, H, key16, hdr32,
        nodelist, z, sd, df, cond, mult, z_embed,
        enc_W1, enc_b1, enc_W2, enc_b2, x0,
        rel_W, lin_W, Wbh, Wbl);
    k_s1<<<13, 256, 0, stream>>>(H, btot);
    k_s2<<<1, 1024, 0, stream>>>(btot, boff);
    k_fill<<<PASSA_B, 256, 0, stream>>>(key16, hdr32, H, boff, packed);
    k_sort2<<<NBKT, 256, 0, stream>>>(packed, boff, off);

    unsigned char* xin = x0; unsigned char* xo = x1;
    for (int l = 0; l < 2; l++) {
        k_fused<<<NBKT, 512, 0, stream>>>((const ushort16*)xin, packed, off,
                                          Wbh + (size_t)l * 512 * 128,
                                          Wbl + (size_t)l * 512 * 128,
                                          lin_b + l * HD, ln_g + l * HD, ln_b + l * HD,
                                          xo);
        unsigned char* t = xin; xin = xo; xo = t;
    }
    k_pool<<<256, 256, 0, stream>>>((const ushort16*)xin, reg_W, reg_b, out);
}

// Round 11
// 511.349 us; speedup vs baseline: 5.0904x; 1.1290x over previous
//
#include <hip/hip_runtime.h>

#define NN 100000
#define NE 1600000
#define HD 128
#define IND 20
#define LNEPS 1e-5f
#define NLIST2 400000   // 4 type regions of NN
#define NBKT 3125       // dst>>5 buckets == k_fused blocks
#define PASSA_B 256
#define EDGES_PER_B 6250
#define FILL_B 256
#define WCAT_B 512
#define ENC_B 12500
#define NWIN 4
#define WINB 782        // buckets per scatter window (4*782 >= 3125)
#define ASTRIDE 260     // A-tile row stride in 32-bit words (520 bf16)
#define SORT_CAP 4096
#define PAD_PER_BKT 224 // 32 nodes * 7 max pad per node
#define NEP (NE + NBKT * PAD_PER_BKT)

typedef unsigned int uint32;
typedef unsigned short ushort16;
typedef __attribute__((ext_vector_type(8))) short bf16x8;
typedef __attribute__((ext_vector_type(4))) float f32x4;
typedef __attribute__((ext_vector_type(2))) float f32x2;

__device__ __forceinline__ ushort16 f2bf(float f) {
    uint32 u = __float_as_uint(f);
    u += 0x7fffu + ((u >> 16) & 1u);   // round-to-nearest-even
    return (ushort16)(u >> 16);
}
__device__ __forceinline__ float bf2f1(ushort16 h) {
    return __uint_as_float(((uint32)h) << 16);
}
__device__ __forceinline__ uint32 pack2bf(float2 v) {
    return (uint32)f2bf(v.x) | ((uint32)f2bf(v.y) << 16);
}

// ---------------- node list (fixed per-type regions) + zero sentinel rows ----------------

__global__ __launch_bounds__(256) void k_fill_n(const int* __restrict__ nt,
                                                int* misc, unsigned* nodelist,
                                                uint32* x0, uint32* x1) {
    int i = blockIdx.x * blockDim.x + threadIdx.x;
    int st = gridDim.x * blockDim.x;
    int lane = threadIdx.x & 63;
    if (blockIdx.x == 399 && threadIdx.x < 32) {     // zero row NN of both x buffers
        x0[(size_t)NN * 32 + threadIdx.x] = 0;
        x1[(size_t)NN * 32 + threadIdx.x] = 0;
    }
    for (int n = i; n < NN; n += st) {
        int t = nt[n];
#pragma unroll
        for (int tt = 0; tt < 4; tt++) {
            unsigned long long m = __ballot(t == tt);
            if (t == tt) {
                int leader = __ffsll((unsigned long long)m) - 1;
                int base = 0;
                if (lane == leader) base = atomicAdd(&misc[8 + tt], (int)__popcll(m));
                base = __shfl(base, leader);
                int prefix = (int)__popcll(m & (((unsigned long long)1 << lane) - 1));
                nodelist[tt * NN + base + prefix] = (unsigned)n | ((unsigned)tt << 17);
            }
        }
    }
}

// ---------------- pass A: per-block bucket histogram + edge records ----------------

__global__ __launch_bounds__(256) void k_hist(const int* __restrict__ ei,
                                              const int* __restrict__ et,
                                              int* __restrict__ H,
                                              ushort16* __restrict__ key16,
                                              unsigned* __restrict__ hdr32) {
    __shared__ int hist[NBKT];
    int bid = blockIdx.x, tid = threadIdx.x;
    for (int k = tid; k < NBKT; k += 256) hist[k] = 0;
    __syncthreads();
    int e0 = bid * EDGES_PER_B, e1 = e0 + EDGES_PER_B;
    for (int e = e0 + tid; e < e1; e += 256) {
        int d = ei[NE + e];
        int s = ei[e];
        int r = et[e];
        int bkt = d >> 5;
        key16[e] = (ushort16)bkt;
        hdr32[e] = (unsigned)s | ((unsigned)r << 17) | ((unsigned)(d & 31) << 19);
        atomicAdd(&hist[bkt], 1);
    }
    __syncthreads();
    for (int k = tid; k < NBKT; k += 256) H[bid * NBKT + k] = hist[k];
}

// ---------------- scans: H column-scan + bucket scan ----------------

__global__ __launch_bounds__(256) void k_s1(int* __restrict__ H, int* __restrict__ btot) {
    int bkt = blockIdx.x * 256 + threadIdx.x;
    if (bkt >= NBKT) return;
    int run = 0;
    for (int jm = 0; jm < PASSA_B; jm += 8) {
        int t0 = H[(jm + 0) * NBKT + bkt];
        int t1 = H[(jm + 1) * NBKT + bkt];
        int t2 = H[(jm + 2) * NBKT + bkt];
        int t3 = H[(jm + 3) * NBKT + bkt];
        int t4 = H[(jm + 4) * NBKT + bkt];
        int t5 = H[(jm + 5) * NBKT + bkt];
        int t6 = H[(jm + 6) * NBKT + bkt];
        int t7 = H[(jm + 7) * NBKT + bkt];
        H[(jm + 0) * NBKT + bkt] = run; run += t0;
        H[(jm + 1) * NBKT + bkt] = run; run += t1;
        H[(jm + 2) * NBKT + bkt] = run; run += t2;
        H[(jm + 3) * NBKT + bkt] = run; run += t3;
        H[(jm + 4) * NBKT + bkt] = run; run += t4;
        H[(jm + 5) * NBKT + bkt] = run; run += t5;
        H[(jm + 6) * NBKT + bkt] = run; run += t6;
        H[(jm + 7) * NBKT + bkt] = run; run += t7;
    }
    btot[bkt] = run;
}

__global__ __launch_bounds__(1024) void k_s2(const int* __restrict__ btot,
                                             int* __restrict__ boff) {
    __shared__ int s[1024];
    int t = threadIdx.x;
    int v4[4];
    int sum = 0;
#pragma unroll
    for (int i = 0; i < 4; i++) {
        int idx = t * 4 + i;
        v4[i] = (idx < NBKT) ? btot[idx] : 0;
        sum += v4[i];
    }
    s[t] = sum;
    __syncthreads();
    for (int o = 1; o < 1024; o <<= 1) {
        int tv = (t >= o) ? s[t - o] : 0;
        __syncthreads();
        s[t] += tv;
        __syncthreads();
    }
    int run = s[t] - sum;
#pragma unroll
    for (int i = 0; i < 4; i++) {
        int idx = t * 4 + i;
        if (idx < NBKT) boff[idx] = run;
        run += v4[i];
    }
    if (t == 1023) boff[NBKT] = NE;
}

// ---------------- merged: windowed scatter | weight-pack | encoder ----------------

#define FMA16(A, v0, v1, v2, v3, w)                                       \
    A[0] += v0.x * w; A[1] += v0.y * w; A[2] += v0.z * w; A[3] += v0.w * w; \
    A[4] += v1.x * w; A[5] += v1.y * w; A[6] += v1.z * w; A[7] += v1.w * w; \
    A[8] += v2.x * w; A[9] += v2.y * w; A[10] += v2.z * w; A[11] += v2.w * w; \
    A[12] += v3.x * w; A[13] += v3.y * w; A[14] += v3.z * w; A[15] += v3.w * w;

__global__ __launch_bounds__(256) void k_fill2(
        const ushort16* __restrict__ key16, const unsigned* __restrict__ hdr32,
        const int* __restrict__ H, const int* __restrict__ boff,
        unsigned* __restrict__ packed,
        const unsigned* __restrict__ nodelist, const int* __restrict__ z,
        const float* __restrict__ sd, const float* __restrict__ df,
        const float* __restrict__ cond, const float* __restrict__ mult,
        const float* __restrict__ z_embed,
        const float* __restrict__ W1, const float* __restrict__ b1,
        const float* __restrict__ W2, const float* __restrict__ b2,
        unsigned char* __restrict__ xout,
        const float* __restrict__ rel_W, const float* __restrict__ lin_W,
        ushort16* __restrict__ Wbh, ushort16* __restrict__ Wbl) {
    __shared__ char smem[21120];   // union: fill cur[782] int | enc raw+h1+ent
    int bid = blockIdx.x;
    int tid = threadIdx.x;

    if (bid < FILL_B) {
        // ---- windowed atomic-free scatter (LDS cursors) ----
        int* cur = (int*)smem;
        int e0 = bid * EDGES_PER_B, e1 = e0 + EDGES_PER_B;
        for (int w = 0; w < NWIN; w++) {
            int lo = w * WINB;
            for (int k = tid; k < WINB; k += 256) {
                int bkt = lo + k;
                cur[k] = (bkt < NBKT) ? (boff[bkt] + H[bid * NBKT + bkt]) : 0;
            }
            __syncthreads();
            for (int e = e0 + tid; e < e1; e += 256) {
                int kb = (int)key16[e];
                unsigned d = (unsigned)(kb - lo);
                if (d < (unsigned)WINB) {
                    int p = atomicAdd(&cur[d], 1);
                    packed[p] = hdr32[e];
                }
            }
            __syncthreads();
        }
        return;
    }
    int j = bid - FILL_B;
    if (j < WCAT_B) {
        // ---- weights -> bf16 B-fragment hi/lo ----
        int idx = j * 256 + tid;           // exactly 2*512*128
        int jj = idx & 7;
        int lane = (idx >> 3) & 63;
        int ntile = (idx >> 9) & 7;
        int kt = (idx >> 12) & 15;
        int l = (idx >> 16) & 1;
        int k = kt * 32 + ((lane >> 4) * 8) + jj;
        int n = ntile * 16 + (lane & 15);
        float v;
        if (k < 384) v = rel_W[((l * 3 + (k >> 7)) * HD + (k & 127)) * HD + n];
        else         v = lin_W[(l * HD + (k - 384)) * HD + n];
        ushort16 hi = f2bf(v);
        Wbh[idx] = hi;
        Wbl[idx] = f2bf(v - bf2f1(hi));
        return;
    }
    j -= WCAT_B;
    if (j >= ENC_B) return;

    // ---- encoder: 32 same-type nodes per block (early-exit on pad blocks) ----
    float (*raw)[20] = (float (*)[20])smem;
    float (*h1)[36]  = (float (*)[36])(smem + 2560);
    unsigned* ent    = (unsigned*)(smem + 20992);

    int base = j * 32;
    if (tid < 32) ent[tid] = nodelist[base + tid];
    __syncthreads();
    if (ent[0] == 0xFFFFFFFFu) return;
    int type = (int)(ent[0] >> 17);

    for (int idx = tid; idx < 32 * 20; idx += 256) {
        int nl = idx / 20, f = idx - nl * 20;
        unsigned e = ent[nl];
        float v = 0.f;
        if (e != 0xFFFFFFFFu) {
            int node = (int)(e & 0x1FFFF);
            if (f < 16)      v = z_embed[z[node] * 16 + f];
            else if (f == 16) v = sd[node];
            else if (f == 17) v = df[node];
            else if (f == 18) v = cond[node];
            else              v = mult[node];
        }
        raw[nl][f] = v;
    }
    __syncthreads();

    int jf = tid & 127, n0 = (tid >> 7) * 16;
    const float* W1t = W1 + type * IND * HD;
    const float* W2t = W2 + type * HD * HD;

    float acc[16];
#pragma unroll
    for (int i = 0; i < 16; i++) acc[i] = 0.f;
    for (int k = 0; k < IND; k++) {
        float w = W1t[k * HD + jf];
#pragma unroll
        for (int i = 0; i < 16; i++) acc[i] += raw[n0 + i][k] * w;
    }
    float bb = b1[type * HD + jf];
#pragma unroll
    for (int i = 0; i < 16; i++) h1[jf][n0 + i] = fmaxf(acc[i] + bb, 0.f);
    __syncthreads();

#pragma unroll
    for (int i = 0; i < 16; i++) acc[i] = 0.f;
    for (int k = 0; k < HD; k++) {
        float w = W2t[k * HD + jf];
        const float4* hp = (const float4*)&h1[k][n0];
        float4 v0 = hp[0], v1 = hp[1], v2 = hp[2], v3 = hp[3];
        FMA16(acc, v0, v1, v2, v3, w)
    }
    float b2v = b2[type * HD + jf];
#pragma unroll
    for (int i = 0; i < 16; i++) {
        unsigned e = ent[n0 + i];
        if (e != 0xFFFFFFFFu) {
            int node = (int)(e & 0x1FFFF);
            float vv = acc[i] + b2v;
            int pk = __builtin_amdgcn_cvt_pk_fp8_f32(vv, vv, 0, false);
            xout[(size_t)node * HD + jf] = (unsigned char)(pk & 0xff);
        }
    }
}

// ---------------- in-bucket counting sort with 8-padding + sentinels ----------------
// One block per bucket: sort by (ldst,rel) into padded layout in packed2
// (each node's segment padded to a multiple of 8 with sentinel src = NN,
// which indexes a zeroed feature row). Writes per-(dst,rel) offsets.

__global__ __launch_bounds__(256) void k_sort2(const unsigned* __restrict__ packed,
                                               const int* __restrict__ boff,
                                               unsigned* __restrict__ packed2,
                                               int* __restrict__ off) {
    __shared__ unsigned ebuf[SORT_CAP];
    __shared__ int hs[96];
    __shared__ int cur[96];
    __shared__ int nend[32];
    __shared__ int npad[33];
    int b = blockIdx.x;
    int tid = threadIdx.x;
    int base = boff[b];
    int tot = boff[b + 1] - base;
    if (tot > SORT_CAP) tot = SORT_CAP;   // statistically impossible (mean 512, sigma 23)
    int pb = base + PAD_PER_BKT * b;

    if (tid < 96) hs[tid] = 0;
    for (int e = tid; e < tot; e += 256) ebuf[e] = packed[base + e];
    __syncthreads();
    for (int e = tid; e < tot; e += 256) {
        unsigned h = ebuf[e];
        int key = (int)(h >> 19) * 3 + (int)((h >> 17) & 3);
        atomicAdd(&hs[key], 1);
    }
    __syncthreads();
    if (tid == 0) {
        int run = 0;
        for (int n = 0; n < 32; n++) {
            npad[n] = run;
            int c0 = hs[3 * n], c1 = hs[3 * n + 1], c2 = hs[3 * n + 2];
            hs[3 * n] = run;
            hs[3 * n + 1] = run + c0;
            hs[3 * n + 2] = run + c0 + c1;
            int c = c0 + c1 + c2;
            nend[n] = run + c;
            run += (c + 7) & ~7;
        }
        npad[32] = run;
    }
    __syncthreads();
    if (tid < 96) {
        cur[tid] = hs[tid];
        off[((b * 32 + tid / 3) << 2) + (tid % 3)] = pb + hs[tid];
    }
    if (tid >= 96 && tid < 128) {
        int n = tid - 96;
        off[((b * 32 + n) << 2) + 3] = pb + nend[n];
    }
    __syncthreads();
    for (int e = tid; e < tot; e += 256) {
        unsigned h = ebuf[e];
        int key = (int)(h >> 19) * 3 + (int)((h >> 17) & 3);
        int p = atomicAdd(&cur[key], 1);
        packed2[pb + p] = h & 0x1FFFF;
    }
    if (tid < 32) {
        for (int q = nend[tid]; q < npad[tid + 1]; q++) packed2[pb + q] = NN;
    }
}

// ---------------- fused layer: register agg (sentinel-padded) -> MFMA -> LN -> fp8 ----------------
// 512 threads = 8 waves; wave w aggregates 4 nodes via a flat 8-wide edge loop
// (no clamps — segments padded to 8 with zero-row sentinels). Prefix-style
// accumulation: a0 unconditional, a1 = rel>=1, a2 = rel>=2; segments by subtraction.

#define EDGE_ACC2(ek, v)                                                     \
    a0x += (v).x; a0y += (v).y;                                              \
    a1x += ((ek) >= bb1) ? (v).x : 0.f; a1y += ((ek) >= bb1) ? (v).y : 0.f;  \
    a2x += ((ek) >= bb2) ? (v).x : 0.f; a2y += ((ek) >= bb2) ? (v).y : 0.f;

__global__ __launch_bounds__(512, 6) void k_fused(
        const ushort16* __restrict__ x,        // fp8 e4m3, 2 features per ushort, row stride 64
        const unsigned* __restrict__ packed,   // src-only, (dst,rel)-sorted, 8-padded w/ sentinels
        const int* __restrict__ off,
        const ushort16* __restrict__ Wbh, const ushort16* __restrict__ Wbl,
        const float* __restrict__ lb, const float* __restrict__ g,
        const float* __restrict__ bta, unsigned char* __restrict__ xout) {
    __shared__ uint32 Alds[32 * ASTRIDE];   // bf16 A-tile [32][520]; aliased as hlds [32][132] f32
    __shared__ float stat[32][2];
    int tid = threadIdx.x;
    int lane = tid & 63;
    int wv = tid >> 6;                     // 0..7
    int nb = blockIdx.x * 32;

    // all boundaries for this wave's 4 nodes in one vector load (16 ints used)
    int bv = off[((nb + wv * 4) << 2) + lane];

    // ---- phase A: flat 8-wide padded edge loop per node ----
#pragma unroll
    for (int i = 0; i < 4; i++) {
        int node = nb + wv * 4 + i;
        int bb0 = __builtin_amdgcn_readlane(bv, 4 * i);
        int bb1 = __builtin_amdgcn_readlane(bv, 4 * i + 1);
        int bb2 = __builtin_amdgcn_readlane(bv, 4 * i + 2);
        int bb3 = __builtin_amdgcn_readlane(bv, 4 * i + 3);
        int deg = bb3 - bb0;
        float id = 1.0f / (float)(deg > 0 ? deg : 1);
        int us = x[(size_t)node * 64 + lane];           // self row (early issue)
        float a0x = 0.f, a0y = 0.f, a1x = 0.f, a1y = 0.f, a2x = 0.f, a2y = 0.f;
        int pe = (deg + 7) & ~7;
        for (int k = 0; k < pe; k += 8) {
            int e = bb0 + k;
            unsigned q0 = packed[e];
            unsigned q1 = packed[e + 1];
            unsigned q2 = packed[e + 2];
            unsigned q3 = packed[e + 3];
            unsigned q4 = packed[e + 4];
            unsigned q5 = packed[e + 5];
            unsigned q6 = packed[e + 6];
            unsigned q7 = packed[e + 7];
            int u0 = x[(size_t)q0 * 64 + lane];
            int u1 = x[(size_t)q1 * 64 + lane];
            int u2 = x[(size_t)q2 * 64 + lane];
            int u3 = x[(size_t)q3 * 64 + lane];
            int u4 = x[(size_t)q4 * 64 + lane];
            int u5 = x[(size_t)q5 * 64 + lane];
            int u6 = x[(size_t)q6 * 64 + lane];
            int u7 = x[(size_t)q7 * 64 + lane];
            f32x2 v0 = __builtin_amdgcn_cvt_pk_f32_fp8(u0, false);
            f32x2 v1 = __builtin_amdgcn_cvt_pk_f32_fp8(u1, false);
            f32x2 v2 = __builtin_amdgcn_cvt_pk_f32_fp8(u2, false);
            f32x2 v3 = __builtin_amdgcn_cvt_pk_f32_fp8(u3, false);
            f32x2 v4 = __builtin_amdgcn_cvt_pk_f32_fp8(u4, false);
            f32x2 v5 = __builtin_amdgcn_cvt_pk_f32_fp8(u5, false);
            f32x2 v6 = __builtin_amdgcn_cvt_pk_f32_fp8(u6, false);
            f32x2 v7 = __builtin_amdgcn_cvt_pk_f32_fp8(u7, false);
            EDGE_ACC2(e, v0)     EDGE_ACC2(e + 1, v1)
            EDGE_ACC2(e + 2, v2) EDGE_ACC2(e + 3, v3)
            EDGE_ACC2(e + 4, v4) EDGE_ACC2(e + 5, v5)
            EDGE_ACC2(e + 6, v6) EDGE_ACC2(e + 7, v7)
        }
        uint32* ar = Alds + (wv * 4 + i) * ASTRIDE;
        float2 s0 = {(a0x - a1x) * id, (a0y - a1y) * id};
        float2 s1 = {(a1x - a2x) * id, (a1y - a2y) * id};
        float2 s2 = {a2x * id, a2y * id};
        f32x2 vs = __builtin_amdgcn_cvt_pk_f32_fp8(us, false);
        float2 s3 = {vs.x, vs.y};
        ar[lane]       = pack2bf(s0);
        ar[64 + lane]  = pack2bf(s1);
        ar[128 + lane] = pack2bf(s2);
        ar[192 + lane] = pack2bf(s3);
    }
    __syncthreads();

    // ---- phase B: MFMA GEMM (W = Whi + Wlo); wave w: n-tile w, m-tiles {0,1} ----
    f32x4 acc00 = {0.f, 0.f, 0.f, 0.f}, acc10 = acc00;
    int mrow0 = (lane & 15);
    int mrow1 = 16 + (lane & 15);
    int q4 = (lane >> 4) * 4;
    const bf16x8* wbh = (const bf16x8*)Wbh;
    const bf16x8* wbl = (const bf16x8*)Wbl;

#pragma unroll 4
    for (int kt = 0; kt < 16; kt++) {
        bf16x8 af0 = *(const bf16x8*)&Alds[mrow0 * ASTRIDE + kt * 16 + q4];
        bf16x8 af1 = *(const bf16x8*)&Alds[mrow1 * ASTRIDE + kt * 16 + q4];
        bf16x8 bh0 = wbh[(kt * 8 + wv) * 64 + lane];
        bf16x8 bl0 = wbl[(kt * 8 + wv) * 64 + lane];
        acc00 = __builtin_amdgcn_mfma_f32_16x16x32_bf16(af0, bh0, acc00, 0, 0, 0);
        acc10 = __builtin_amdgcn_mfma_f32_16x16x32_bf16(af1, bh0, acc10, 0, 0, 0);
        acc00 = __builtin_amdgcn_mfma_f32_16x16x32_bf16(af0, bl0, acc00, 0, 0, 0);
        acc10 = __builtin_amdgcn_mfma_f32_16x16x32_bf16(af1, bl0, acc10, 0, 0, 0);
    }
    __syncthreads();   // A-tile reads done; alias as hlds

    // ---- bias into LDS for LN stats ----
    float* hlds = (float*)Alds;            // [32][132]
    int n0 = wv * 16 + (lane & 15);
    float bj0 = lb[n0];
    int rbase = (lane >> 4) * 4;
#pragma unroll
    for (int r = 0; r < 4; r++) {
        hlds[(rbase + r) * 132 + n0]      = acc00[r] + bj0;
        hlds[(16 + rbase + r) * 132 + n0] = acc10[r] + bj0;
    }
    __syncthreads();

    {
        int node = tid >> 4, l16 = tid & 15;
        float s = 0.f, ss = 0.f;
#pragma unroll
        for (int i = 0; i < 8; i++) {
            float v = hlds[node * 132 + l16 + 16 * i];
            s += v; ss += v * v;
        }
        for (int d = 8; d >= 1; d >>= 1) {
            s += __shfl_down(s, d, 16);
            ss += __shfl_down(ss, d, 16);
        }
        if (l16 == 0) {
            float mu = s * (1.f / 128.f);
            float var = ss * (1.f / 128.f) - mu * mu;
            stat[node][0] = mu;
            stat[node][1] = rsqrtf(var + LNEPS);
        }
    }
    __syncthreads();

    // ---- LN epilogue + fp8 repack (8B per thread, coalesced) ----
    {
        int node = tid >> 4, q16 = tid & 15;
        float mu = stat[node][0], rs = stat[node][1];
        const float* hr = hlds + node * 132 + q16 * 8;
        int w[2];
#pragma unroll
        for (int p = 0; p < 2; p++) {
            int f = q16 * 8 + p * 4;
            float v0 = (hr[p * 4 + 0] - mu) * rs * g[f + 0] + bta[f + 0];
            float v1 = (hr[p * 4 + 1] - mu) * rs * g[f + 1] + bta[f + 1];
            float v2 = (hr[p * 4 + 2] - mu) * rs * g[f + 2] + bta[f + 2];
            float v3 = (hr[p * 4 + 3] - mu) * rs * g[f + 3] + bta[f + 3];
            int pk = __builtin_amdgcn_cvt_pk_fp8_f32(v0, v1, 0, false);
            pk = __builtin_amdgcn_cvt_pk_fp8_f32(v2, v3, pk, true);
            w[p] = pk;
        }
        *(int2*)(xout + (size_t)(nb + node) * 128 + q16 * 8) = make_int2(w[0], w[1]);
    }
}

// ---------------- pooling + regressor ----------------

__global__ __launch_bounds__(256) void k_pool(const ushort16* __restrict__ x,
                                              const float* regW, const float* reg_b,
                                              float* out) {
    int tid = threadIdx.x;
    int p = tid & 63;
    float sx = 0.f, sy = 0.f;
    int row = blockIdx.x * 4 + (tid >> 6);
    for (; row < NN; row += gridDim.x * 4) {
        int u = x[(size_t)row * 64 + p];
        f32x2 v = __builtin_amdgcn_cvt_pk_f32_fp8(u, false);
        sx += v.x; sy += v.y;
    }
    float s = sx * regW[2 * p] + sy * regW[2 * p + 1];
    for (int d = 32; d >= 1; d >>= 1) s += __shfl_down(s, d);
    __shared__ float red[4];
    if ((tid & 63) == 0) red[tid >> 6] = s;
    __syncthreads();
    if (tid == 0) {
        float t = (red[0] + red[1] + red[2] + red[3]) * (1.0f / (float)NN);
        if (blockIdx.x == 0) t += reg_b[0];
        atomicAdd(out, t);
    }
}

// ---------------- launcher ----------------

extern "C" void kernel_launch(void* const* d_in, const int* in_sizes, int n_in,
                              void* d_out, int out_size, void* d_ws, size_t ws_size,
                              hipStream_t stream) {
    const int*   z       = (const int*)d_in[0];
    const float* sd      = (const float*)d_in[1];
    const float* df      = (const float*)d_in[2];
    const float* cond    = (const float*)d_in[3];
    const float* mult    = (const float*)d_in[4];
    const int*   nt      = (const int*)d_in[5];
    const int*   ei      = (const int*)d_in[6];
    const int*   et      = (const int*)d_in[7];
    const float* z_embed = (const float*)d_in[8];
    const float* enc_W1  = (const float*)d_in[9];
    const float* enc_b1  = (const float*)d_in[10];
    const float* enc_W2  = (const float*)d_in[11];
    const float* enc_b2  = (const float*)d_in[12];
    const float* lin_W   = (const float*)d_in[13];
    const float* lin_b   = (const float*)d_in[14];
    const float* rel_W   = (const float*)d_in[15];
    const float* ln_g    = (const float*)d_in[16];
    const float* ln_b    = (const float*)d_in[17];
    const float* reg_W   = (const float*)d_in[18];
    const float* reg_b   = (const float*)d_in[19];
    float* out = (float*)d_out;

    char* p = (char*)d_ws;
    int* H          = (int*)p;      p += (size_t)PASSA_B * NBKT * 4;   // 3.2 MB
    int* btot       = (int*)p;      p += (size_t)4096 * 4;
    int* boff       = (int*)p;      p += (size_t)4096 * 4;
    int* misc       = (int*)p;      p += 16 * 4;
    int* off        = (int*)p;      p += (size_t)400384 * 4;
    ushort16* key16 = (ushort16*)p; p += (size_t)NE * 2;
    unsigned* hdr32 = (unsigned*)p; p += (size_t)NE * 4;
    unsigned* packed   = (unsigned*)p; p += (size_t)NE * 4;
    unsigned* packed2  = (unsigned*)p; p += (size_t)NEP * 4;
    unsigned* nodelist = (unsigned*)p; p += (size_t)NLIST2 * 4;
    ushort16* Wbh   = (ushort16*)p; p += (size_t)2 * 512 * 128 * 2;
    ushort16* Wbl   = (ushort16*)p; p += (size_t)2 * 512 * 128 * 2;
    unsigned char* x0 = (unsigned char*)p; p += (size_t)(NN + 1) * HD;
    unsigned char* x1 = (unsigned char*)p; p += (size_t)(NN + 1) * HD;

    hipMemsetAsync(misc, 0, 64, stream);
    hipMemsetAsync(nodelist, 0xFF, (size_t)NLIST2 * 4, stream);
    hipMemsetAsync(out, 0, 4, stream);

    k_fill_n<<<400, 256, 0, stream>>>(nt, misc, nodelist, (uint32*)x0, (uint32*)x1);
    k_hist<<<PASSA_B, 256, 0, stream>>>(ei, et, H, key16, hdr32);
    k_s1<<<13, 256, 0, stream>>>(H, btot);
    k_s2<<<1, 1024, 0, stream>>>(btot, boff);
    k_fill2<<<FILL_B + WCAT_B + ENC_B, 256, 0, stream>>>(
        key16, hdr32, H, boff, packed,
        nodelist, z, sd, df, cond, mult, z_embed,
        enc_W1, enc_b1, enc_W2, enc_b2, x0,
        rel_W, lin_W, Wbh, Wbl);
    k_sort2<<<NBKT, 256, 0, stream>>>(packed, boff, packed2, off);

    unsigned char* xin = x0; unsigned char* xo = x1;
    for (int l = 0; l < 2; l++) {
        k_fused<<<NBKT, 512, 0, stream>>>((const ushort16*)xin, packed2, off,
                                          Wbh + (size_t)l * 512 * 128,
                                          Wbl + (size_t)l * 512 * 128,
                                          lin_b + l * HD, ln_g + l * HD, ln_b + l * HD,
                                          xo);
        unsigned char* t = xin; xin = xo; xo = t;
    }
    k_pool<<<256, 256, 0, stream>>>((const ushort16*)xin, reg_W, reg_b, out);
}

// Round 13
// 488.403 us; speedup vs baseline: 5.3296x; 1.0470x over previous
//
#include <hip/hip_runtime.h>

#define NN 100000
#define NE 1600000
#define HD 128
#define IND 20
#define LNEPS 1e-5f
#define NLIST2 400000   // 4 type regions of NN
#define NBKT 3125       // dst>>5 buckets == k_fused blocks
#define PASSA_B 256
#define EDGES_PER_B 6250
#define FILL_B 256
#define WCAT_B 512
#define WCATE_B 256
#define ENC_B 12500
#define NWIN 4
#define WINB 782        // buckets per scatter window (4*782 >= 3125)
#define ASTRIDE 260     // A-tile row stride in 32-bit words (520 bf16)
#define SORT_CAP 4096
#define PAD_PER_BKT 672 // 96 segments * up to 7 pad each
#define NEP (NE + NBKT * PAD_PER_BKT)
#define H1S 136         // enc h1 row stride in bf16 (272 B, 16B-aligned rows)

typedef unsigned int uint32;
typedef unsigned short ushort16;
typedef __attribute__((ext_vector_type(8))) short bf16x8;
typedef __attribute__((ext_vector_type(4))) float f32x4;
typedef __attribute__((ext_vector_type(2))) float f32x2;

__device__ __forceinline__ ushort16 f2bf(float f) {
    uint32 u = __float_as_uint(f);
    u += 0x7fffu + ((u >> 16) & 1u);   // round-to-nearest-even
    return (ushort16)(u >> 16);
}
__device__ __forceinline__ float bf2f1(ushort16 h) {
    return __uint_as_float(((uint32)h) << 16);
}
__device__ __forceinline__ uint32 pack2bf(float2 v) {
    return (uint32)f2bf(v.x) | ((uint32)f2bf(v.y) << 16);
}

// ---------------- node list (fixed per-type regions) + zero sentinel rows ----------------

__global__ __launch_bounds__(256) void k_fill_n(const int* __restrict__ nt,
                                                int* misc, unsigned* nodelist,
                                                uint32* x0, uint32* x1) {
    int i = blockIdx.x * blockDim.x + threadIdx.x;
    int st = gridDim.x * blockDim.x;
    int lane = threadIdx.x & 63;
    if (blockIdx.x == 399 && threadIdx.x < 32) {     // zero row NN of both x buffers
        x0[(size_t)NN * 32 + threadIdx.x] = 0;
        x1[(size_t)NN * 32 + threadIdx.x] = 0;
    }
    for (int n = i; n < NN; n += st) {
        int t = nt[n];
#pragma unroll
        for (int tt = 0; tt < 4; tt++) {
            unsigned long long m = __ballot(t == tt);
            if (t == tt) {
                int leader = __ffsll((unsigned long long)m) - 1;
                int base = 0;
                if (lane == leader) base = atomicAdd(&misc[8 + tt], (int)__popcll(m));
                base = __shfl(base, leader);
                int prefix = (int)__popcll(m & (((unsigned long long)1 << lane) - 1));
                nodelist[tt * NN + base + prefix] = (unsigned)n | ((unsigned)tt << 17);
            }
        }
    }
}

// ---------------- pass A: bucket histogram + edge records | enc-W2 pack ----------------
// WCATE role lives HERE (not in k_fill2) so Weh/Wel are complete before the
// k_fill2 dispatch whose enc role consumes them (same-dispatch order is undefined).

__global__ __launch_bounds__(256) void k_hist(const int* __restrict__ ei,
                                              const int* __restrict__ et,
                                              int* __restrict__ H,
                                              ushort16* __restrict__ key16,
                                              unsigned* __restrict__ hdr32,
                                              const float* __restrict__ W2,
                                              ushort16* __restrict__ Weh,
                                              ushort16* __restrict__ Wel) {
    __shared__ int hist[NBKT];
    int bid = blockIdx.x, tid = threadIdx.x;

    if (bid >= PASSA_B) {
        // ---- enc W2 (per type) -> bf16 B-fragment hi/lo ----
        int idx = (bid - PASSA_B) * 256 + tid;   // exactly 4*4*8*64*8 = 65536
        int jj = idx & 7;
        int lane = (idx >> 3) & 63;
        int ntile = (idx >> 9) & 7;
        int kt = (idx >> 12) & 3;
        int t = (idx >> 14) & 3;
        int k = kt * 32 + ((lane >> 4) * 8) + jj;
        int n = ntile * 16 + (lane & 15);
        float v = W2[((size_t)t * HD + k) * HD + n];
        ushort16 hi = f2bf(v);
        Weh[idx] = hi;
        Wel[idx] = f2bf(v - bf2f1(hi));
        return;
    }

    for (int k = tid; k < NBKT; k += 256) hist[k] = 0;
    __syncthreads();
    int e0 = bid * EDGES_PER_B, e1 = e0 + EDGES_PER_B;
    for (int e = e0 + tid; e < e1; e += 256) {
        int d = ei[NE + e];
        int s = ei[e];
        int r = et[e];
        int bkt = d >> 5;
        key16[e] = (ushort16)bkt;
        hdr32[e] = (unsigned)s | ((unsigned)r << 17) | ((unsigned)(d & 31) << 19);
        atomicAdd(&hist[bkt], 1);
    }
    __syncthreads();
    for (int k = tid; k < NBKT; k += 256) H[bid * NBKT + k] = hist[k];
}

// ---------------- scans: H column-scan + bucket scan ----------------

__global__ __launch_bounds__(256) void k_s1(int* __restrict__ H, int* __restrict__ btot) {
    int bkt = blockIdx.x * 256 + threadIdx.x;
    if (bkt >= NBKT) return;
    int run = 0;
    for (int jm = 0; jm < PASSA_B; jm += 8) {
        int t0 = H[(jm + 0) * NBKT + bkt];
        int t1 = H[(jm + 1) * NBKT + bkt];
        int t2 = H[(jm + 2) * NBKT + bkt];
        int t3 = H[(jm + 3) * NBKT + bkt];
        int t4 = H[(jm + 4) * NBKT + bkt];
        int t5 = H[(jm + 5) * NBKT + bkt];
        int t6 = H[(jm + 6) * NBKT + bkt];
        int t7 = H[(jm + 7) * NBKT + bkt];
        H[(jm + 0) * NBKT + bkt] = run; run += t0;
        H[(jm + 1) * NBKT + bkt] = run; run += t1;
        H[(jm + 2) * NBKT + bkt] = run; run += t2;
        H[(jm + 3) * NBKT + bkt] = run; run += t3;
        H[(jm + 4) * NBKT + bkt] = run; run += t4;
        H[(jm + 5) * NBKT + bkt] = run; run += t5;
        H[(jm + 6) * NBKT + bkt] = run; run += t6;
        H[(jm + 7) * NBKT + bkt] = run; run += t7;
    }
    btot[bkt] = run;
}

__global__ __launch_bounds__(1024) void k_s2(const int* __restrict__ btot,
                                             int* __restrict__ boff) {
    __shared__ int s[1024];
    int t = threadIdx.x;
    int v4[4];
    int sum = 0;
#pragma unroll
    for (int i = 0; i < 4; i++) {
        int idx = t * 4 + i;
        v4[i] = (idx < NBKT) ? btot[idx] : 0;
        sum += v4[i];
    }
    s[t] = sum;
    __syncthreads();
    for (int o = 1; o < 1024; o <<= 1) {
        int tv = (t >= o) ? s[t - o] : 0;
        __syncthreads();
        s[t] += tv;
        __syncthreads();
    }
    int run = s[t] - sum;
#pragma unroll
    for (int i = 0; i < 4; i++) {
        int idx = t * 4 + i;
        if (idx < NBKT) boff[idx] = run;
        run += v4[i];
    }
    if (t == 1023) boff[NBKT] = NE;
}

// ---------------- merged: windowed scatter | layer-W pack | encoder ----------------

__global__ __launch_bounds__(256) void k_fill2(
        const ushort16* __restrict__ key16, const unsigned* __restrict__ hdr32,
        const int* __restrict__ H, const int* __restrict__ boff,
        unsigned* __restrict__ packed,
        const unsigned* __restrict__ nodelist, const int* __restrict__ z,
        const float* __restrict__ sd, const float* __restrict__ df,
        const float* __restrict__ cond, const float* __restrict__ mult,
        const float* __restrict__ z_embed,
        const float* __restrict__ W1, const float* __restrict__ b1,
        const float* __restrict__ b2,
        unsigned char* __restrict__ xout,
        const float* __restrict__ rel_W, const float* __restrict__ lin_W,
        ushort16* __restrict__ Wbh, ushort16* __restrict__ Wbl,
        const ushort16* __restrict__ Weh, const ushort16* __restrict__ Wel) {
    __shared__ __attribute__((aligned(16))) char smem[11456];
    // union: fill cur[782] int | enc raw(2560)+h1b(8704)+ent(128)
    int bid = blockIdx.x;
    int tid = threadIdx.x;

    if (bid < FILL_B) {
        // ---- windowed atomic-free scatter (LDS cursors) ----
        int* cur = (int*)smem;
        int e0 = bid * EDGES_PER_B, e1 = e0 + EDGES_PER_B;
        for (int w = 0; w < NWIN; w++) {
            int lo = w * WINB;
            for (int k = tid; k < WINB; k += 256) {
                int bkt = lo + k;
                cur[k] = (bkt < NBKT) ? (boff[bkt] + H[bid * NBKT + bkt]) : 0;
            }
            __syncthreads();
            for (int e = e0 + tid; e < e1; e += 256) {
                int kb = (int)key16[e];
                unsigned d = (unsigned)(kb - lo);
                if (d < (unsigned)WINB) {
                    int p = atomicAdd(&cur[d], 1);
                    packed[p] = hdr32[e];
                }
            }
            __syncthreads();
        }
        return;
    }
    int j = bid - FILL_B;
    if (j < WCAT_B) {
        // ---- layer weights -> bf16 B-fragment hi/lo (consumed by later dispatch) ----
        int idx = j * 256 + tid;           // exactly 2*512*128
        int jj = idx & 7;
        int lane = (idx >> 3) & 63;
        int ntile = (idx >> 9) & 7;
        int kt = (idx >> 12) & 15;
        int l = (idx >> 16) & 1;
        int k = kt * 32 + ((lane >> 4) * 8) + jj;
        int n = ntile * 16 + (lane & 15);
        float v;
        if (k < 384) v = rel_W[((l * 3 + (k >> 7)) * HD + (k & 127)) * HD + n];
        else         v = lin_W[(l * HD + (k - 384)) * HD + n];
        ushort16 hi = f2bf(v);
        Wbh[idx] = hi;
        Wbl[idx] = f2bf(v - bf2f1(hi));
        return;
    }
    j -= WCAT_B;
    if (j >= ENC_B) return;

    // ---- encoder: 32 same-type nodes; layer1 VALU -> bf16 h1 -> layer2 MFMA ----
    float (*raw)[20]   = (float (*)[20])smem;
    ushort16* h1b      = (ushort16*)(smem + 2560);       // [32][H1S] bf16
    unsigned* ent      = (unsigned*)(smem + 2560 + 8704);

    int base = j * 32;
    if (tid < 32) ent[tid] = nodelist[base + tid];
    __syncthreads();
    if (ent[0] == 0xFFFFFFFFu) return;
    int type = (int)(ent[0] >> 17);

    for (int idx = tid; idx < 32 * 20; idx += 256) {
        int nl = idx / 20, f = idx - nl * 20;
        unsigned e = ent[nl];
        float v = 0.f;
        if (e != 0xFFFFFFFFu) {
            int node = (int)(e & 0x1FFFF);
            if (f < 16)      v = z_embed[z[node] * 16 + f];
            else if (f == 16) v = sd[node];
            else if (f == 17) v = df[node];
            else if (f == 18) v = cond[node];
            else              v = mult[node];
        }
        raw[nl][f] = v;
    }
    __syncthreads();

    int jf = tid & 127, n0 = (tid >> 7) * 16;
    const float* W1t = W1 + type * IND * HD;

    float acc[16];
#pragma unroll
    for (int i = 0; i < 16; i++) acc[i] = 0.f;
    for (int k = 0; k < IND; k++) {
        float w = W1t[k * HD + jf];
#pragma unroll
        for (int i = 0; i < 16; i++) acc[i] += raw[n0 + i][k] * w;
    }
    float bb = b1[type * HD + jf];
#pragma unroll
    for (int i = 0; i < 16; i++) h1b[(n0 + i) * H1S + jf] = f2bf(fmaxf(acc[i] + bb, 0.f));
    __syncthreads();

    // layer2: D[32x128] = h1[32x128] @ W2[type] via MFMA hi/lo
    int lane = tid & 63, wv = tid >> 6;
    int nt0 = 2 * wv, nt1 = 2 * wv + 1;
    f32x4 a00 = {0.f, 0.f, 0.f, 0.f}, a01 = a00, a10 = a00, a11 = a00;
    int mrow0 = lane & 15, mrow1 = 16 + (lane & 15);
    int koff = (lane >> 4) * 8;
    const bf16x8* weh = (const bf16x8*)(Weh + (size_t)type * 16384);
    const bf16x8* wel = (const bf16x8*)(Wel + (size_t)type * 16384);
    const ushort16* h1p = h1b;
#pragma unroll
    for (int kt = 0; kt < 4; kt++) {
        bf16x8 af0 = *(const bf16x8*)&h1p[mrow0 * H1S + kt * 32 + koff];
        bf16x8 af1 = *(const bf16x8*)&h1p[mrow1 * H1S + kt * 32 + koff];
        bf16x8 bh0 = weh[(kt * 8 + nt0) * 64 + lane];
        bf16x8 bh1 = weh[(kt * 8 + nt1) * 64 + lane];
        bf16x8 bl0 = wel[(kt * 8 + nt0) * 64 + lane];
        bf16x8 bl1 = wel[(kt * 8 + nt1) * 64 + lane];
        a00 = __builtin_amdgcn_mfma_f32_16x16x32_bf16(af0, bh0, a00, 0, 0, 0);
        a01 = __builtin_amdgcn_mfma_f32_16x16x32_bf16(af0, bh1, a01, 0, 0, 0);
        a10 = __builtin_amdgcn_mfma_f32_16x16x32_bf16(af1, bh0, a10, 0, 0, 0);
        a11 = __builtin_amdgcn_mfma_f32_16x16x32_bf16(af1, bh1, a11, 0, 0, 0);
        a00 = __builtin_amdgcn_mfma_f32_16x16x32_bf16(af0, bl0, a00, 0, 0, 0);
        a01 = __builtin_amdgcn_mfma_f32_16x16x32_bf16(af0, bl1, a01, 0, 0, 0);
        a10 = __builtin_amdgcn_mfma_f32_16x16x32_bf16(af1, bl0, a10, 0, 0, 0);
        a11 = __builtin_amdgcn_mfma_f32_16x16x32_bf16(af1, bl1, a11, 0, 0, 0);
    }
    int c0 = nt0 * 16 + (lane & 15), c1 = nt1 * 16 + (lane & 15);
    float b20 = b2[type * HD + c0], b21 = b2[type * HD + c1];
    int rb = (lane >> 4) * 4;
#pragma unroll
    for (int r = 0; r < 4; r++) {
        int r0 = rb + r, r1 = 16 + rb + r;
        unsigned e0v = ent[r0], e1v = ent[r1];
        if (e0v != 0xFFFFFFFFu) {
            int node = (int)(e0v & 0x1FFFF);
            int p0 = __builtin_amdgcn_cvt_pk_fp8_f32(a00[r] + b20, a00[r] + b20, 0, false);
            int p1 = __builtin_amdgcn_cvt_pk_fp8_f32(a01[r] + b21, a01[r] + b21, 0, false);
            xout[(size_t)node * HD + c0] = (unsigned char)(p0 & 0xff);
            xout[(size_t)node * HD + c1] = (unsigned char)(p1 & 0xff);
        }
        if (e1v != 0xFFFFFFFFu) {
            int node = (int)(e1v & 0x1FFFF);
            int p0 = __builtin_amdgcn_cvt_pk_fp8_f32(a10[r] + b20, a10[r] + b20, 0, false);
            int p1 = __builtin_amdgcn_cvt_pk_fp8_f32(a11[r] + b21, a11[r] + b21, 0, false);
            xout[(size_t)node * HD + c0] = (unsigned char)(p0 & 0xff);
            xout[(size_t)node * HD + c1] = (unsigned char)(p1 & 0xff);
        }
    }
}

// ---------------- in-bucket counting sort: per-(dst,rel) segments padded to 8 ----------------

__global__ __launch_bounds__(256) void k_sort2(const unsigned* __restrict__ packed,
                                               const int* __restrict__ boff,
                                               unsigned* __restrict__ packed2,
                                               int* __restrict__ off,
                                               int* __restrict__ degarr) {
    __shared__ unsigned ebuf[SORT_CAP];
    __shared__ int hs[96];
    __shared__ int cur[96];
    __shared__ int segp[97];   // padded segment starts (96) + end
    int b = blockIdx.x;
    int tid = threadIdx.x;
    int base = boff[b];
    int tot = boff[b + 1] - base;
    if (tot > SORT_CAP) tot = SORT_CAP;   // statistically impossible (mean 512, sigma 23)
    int pb = base + PAD_PER_BKT * b;

    if (tid < 96) hs[tid] = 0;
    for (int e = tid; e < tot; e += 256) ebuf[e] = packed[base + e];
    __syncthreads();
    for (int e = tid; e < tot; e += 256) {
        unsigned h = ebuf[e];
        int key = (int)(h >> 19) * 3 + (int)((h >> 17) & 3);
        atomicAdd(&hs[key], 1);
    }
    __syncthreads();
    if (tid == 0) {
        int run = 0;
        for (int k = 0; k < 96; k++) {
            segp[k] = run;
            run += (hs[k] + 7) & ~7;
        }
        segp[96] = run;
    }
    __syncthreads();
    if (tid < 96) {
        cur[tid] = segp[tid];
        off[((b * 32 + tid / 3) << 2) + (tid % 3)] = pb + segp[tid];
    }
    if (tid >= 96 && tid < 128) {
        int n = tid - 96;
        off[((b * 32 + n) << 2) + 3] = pb + segp[3 * n + 3];
        degarr[b * 32 + n] = hs[3 * n] + hs[3 * n + 1] + hs[3 * n + 2];
    }
    __syncthreads();
    for (int e = tid; e < tot; e += 256) {
        unsigned h = ebuf[e];
        int key = (int)(h >> 19) * 3 + (int)((h >> 17) & 3);
        int p = atomicAdd(&cur[key], 1);
        packed2[pb + p] = h & 0x1FFFF;
    }
    __syncthreads();
    if (tid < 96) {   // sentinel-fill each segment's tail
        int e0 = segp[tid] + hs[tid];
        int e1 = segp[tid + 1];
        for (int q = e0; q < e1; q++) packed2[pb + q] = NN;
    }
}

// ---------------- fused layer: register agg (pure-rel 8-groups) -> MFMA -> LN -> fp8 ----------------
// 512 threads = 8 waves; wave w aggregates 4 nodes. Every 8-group lies inside
// one rel segment (segments padded to 8 with zero-row sentinels) -> scalar
// 3-way branch picks the accumulator; adds unconditional. 32-bit addressing.

#define ADD8(AX, AY)                                                         \
    AX += v0.x + v1.x; AY += v0.y + v1.y;                                    \
    AX += v2.x + v3.x; AY += v2.y + v3.y;                                    \
    AX += v4.x + v5.x; AY += v4.y + v5.y;                                    \
    AX += v6.x + v7.x; AY += v6.y + v7.y;

__global__ __launch_bounds__(512, 6) void k_fused(
        const ushort16* __restrict__ x,        // fp8 e4m3, 2 features per ushort, row stride 64
        const unsigned* __restrict__ packed,   // src-only, (dst,rel)-sorted, seg-8-padded
        const int* __restrict__ off, const int* __restrict__ degarr,
        const ushort16* __restrict__ Wbh, const ushort16* __restrict__ Wbl,
        const float* __restrict__ lb, const float* __restrict__ g,
        const float* __restrict__ bta, unsigned char* __restrict__ xout) {
    __shared__ uint32 Alds[32 * ASTRIDE];   // bf16 A-tile [32][520]; aliased as hlds [32][132] f32
    __shared__ float stat[32][2];
    int tid = threadIdx.x;
    int lane = tid & 63;
    int wv = tid >> 6;                     // 0..7
    int nb = blockIdx.x * 32;

    int bv = off[((nb + wv * 4) << 2) + lane];        // 16 boundaries for 4 nodes
    int dgv = degarr[nb + wv * 4 + (lane & 3)];       // real degrees

    // ---- phase A ----
#pragma unroll
    for (int i = 0; i < 4; i++) {
        int node = nb + wv * 4 + i;
        int bb0 = __builtin_amdgcn_readlane(bv, 4 * i);
        int bb1 = __builtin_amdgcn_readlane(bv, 4 * i + 1);
        int bb2 = __builtin_amdgcn_readlane(bv, 4 * i + 2);
        int bb3 = __builtin_amdgcn_readlane(bv, 4 * i + 3);
        int rdeg = __builtin_amdgcn_readlane(dgv, i);
        float id = 1.0f / (float)(rdeg > 0 ? rdeg : 1);
        int us = x[node * 64 + lane];                 // self row (early issue)
        float a0x = 0.f, a0y = 0.f, a1x = 0.f, a1y = 0.f, a2x = 0.f, a2y = 0.f;
        for (int e = bb0; e < bb3; e += 8) {
            unsigned q0 = packed[e];
            unsigned q1 = packed[e + 1];
            unsigned q2 = packed[e + 2];
            unsigned q3 = packed[e + 3];
            unsigned q4 = packed[e + 4];
            unsigned q5 = packed[e + 5];
            unsigned q6 = packed[e + 6];
            unsigned q7 = packed[e + 7];
            int u0 = x[(int)q0 * 64 + lane];
            int u1 = x[(int)q1 * 64 + lane];
            int u2 = x[(int)q2 * 64 + lane];
            int u3 = x[(int)q3 * 64 + lane];
            int u4 = x[(int)q4 * 64 + lane];
            int u5 = x[(int)q5 * 64 + lane];
            int u6 = x[(int)q6 * 64 + lane];
            int u7 = x[(int)q7 * 64 + lane];
            f32x2 v0 = __builtin_amdgcn_cvt_pk_f32_fp8(u0, false);
            f32x2 v1 = __builtin_amdgcn_cvt_pk_f32_fp8(u1, false);
            f32x2 v2 = __builtin_amdgcn_cvt_pk_f32_fp8(u2, false);
            f32x2 v3 = __builtin_amdgcn_cvt_pk_f32_fp8(u3, false);
            f32x2 v4 = __builtin_amdgcn_cvt_pk_f32_fp8(u4, false);
            f32x2 v5 = __builtin_amdgcn_cvt_pk_f32_fp8(u5, false);
            f32x2 v6 = __builtin_amdgcn_cvt_pk_f32_fp8(u6, false);
            f32x2 v7 = __builtin_amdgcn_cvt_pk_f32_fp8(u7, false);
            if (e < bb1)      { ADD8(a0x, a0y) }
            else if (e < bb2) { ADD8(a1x, a1y) }
            else              { ADD8(a2x, a2y) }
        }
        uint32* ar = Alds + (wv * 4 + i) * ASTRIDE;
        float2 s0 = {a0x * id, a0y * id};
        float2 s1 = {a1x * id, a1y * id};
        float2 s2 = {a2x * id, a2y * id};
        f32x2 vs = __builtin_amdgcn_cvt_pk_f32_fp8(us, false);
        float2 s3 = {vs.x, vs.y};
        ar[lane]       = pack2bf(s0);
        ar[64 + lane]  = pack2bf(s1);
        ar[128 + lane] = pack2bf(s2);
        ar[192 + lane] = pack2bf(s3);
    }
    __syncthreads();

    // ---- phase B: MFMA GEMM (W = Whi + Wlo); wave w: n-tile w, m-tiles {0,1} ----
    f32x4 acc00 = {0.f, 0.f, 0.f, 0.f}, acc10 = acc00;
    int mrow0 = (lane & 15);
    int mrow1 = 16 + (lane & 15);
    int q4 = (lane >> 4) * 4;
    const bf16x8* wbh = (const bf16x8*)Wbh;
    const bf16x8* wbl = (const bf16x8*)Wbl;

#pragma unroll 4
    for (int kt = 0; kt < 16; kt++) {
        bf16x8 af0 = *(const bf16x8*)&Alds[mrow0 * ASTRIDE + kt * 16 + q4];
        bf16x8 af1 = *(const bf16x8*)&Alds[mrow1 * ASTRIDE + kt * 16 + q4];
        bf16x8 bh0 = wbh[(kt * 8 + wv) * 64 + lane];
        bf16x8 bl0 = wbl[(kt * 8 + wv) * 64 + lane];
        acc00 = __builtin_amdgcn_mfma_f32_16x16x32_bf16(af0, bh0, acc00, 0, 0, 0);
        acc10 = __builtin_amdgcn_mfma_f32_16x16x32_bf16(af1, bh0, acc10, 0, 0, 0);
        acc00 = __builtin_amdgcn_mfma_f32_16x16x32_bf16(af0, bl0, acc00, 0, 0, 0);
        acc10 = __builtin_amdgcn_mfma_f32_16x16x32_bf16(af1, bl0, acc10, 0, 0, 0);
    }
    __syncthreads();   // A-tile reads done; alias as hlds

    // ---- bias into LDS for LN stats ----
    float* hlds = (float*)Alds;            // [32][132]
    int n0 = wv * 16 + (lane & 15);
    float bj0 = lb[n0];
    int rbase = (lane >> 4) * 4;
#pragma unroll
    for (int r = 0; r < 4; r++) {
        hlds[(rbase + r) * 132 + n0]      = acc00[r] + bj0;
        hlds[(16 + rbase + r) * 132 + n0] = acc10[r] + bj0;
    }
    __syncthreads();

    {
        int node = tid >> 4, l16 = tid & 15;
        float s = 0.f, ss = 0.f;
#pragma unroll
        for (int i = 0; i < 8; i++) {
            float v = hlds[node * 132 + l16 + 16 * i];
            s += v; ss += v * v;
        }
        for (int d = 8; d >= 1; d >>= 1) {
            s += __shfl_down(s, d, 16);
            ss += __shfl_down(ss, d, 16);
        }
        if (l16 == 0) {
            float mu = s * (1.f / 128.f);
            float var = ss * (1.f / 128.f) - mu * mu;
            stat[node][0] = mu;
            stat[node][1] = rsqrtf(var + LNEPS);
        }
    }
    __syncthreads();

    // ---- LN epilogue + fp8 repack (8B per thread, coalesced) ----
    {
        int node = tid >> 4, q16 = tid & 15;
        float mu = stat[node][0], rs = stat[node][1];
        const float* hr = hlds + node * 132 + q16 * 8;
        int w[2];
#pragma unroll
        for (int p = 0; p < 2; p++) {
            int f = q16 * 8 + p * 4;
            float v0 = (hr[p * 4 + 0] - mu) * rs * g[f + 0] + bta[f + 0];
            float v1 = (hr[p * 4 + 1] - mu) * rs * g[f + 1] + bta[f + 1];
            float v2 = (hr[p * 4 + 2] - mu) * rs * g[f + 2] + bta[f + 2];
            float v3 = (hr[p * 4 + 3] - mu) * rs * g[f + 3] + bta[f + 3];
            int pk = __builtin_amdgcn_cvt_pk_fp8_f32(v0, v1, 0, false);
            pk = __builtin_amdgcn_cvt_pk_fp8_f32(v2, v3, pk, true);
            w[p] = pk;
        }
        *(int2*)(xout + (size_t)(nb + node) * 128 + q16 * 8) = make_int2(w[0], w[1]);
    }
}

// ---------------- pooling + regressor ----------------

__global__ __launch_bounds__(256) void k_pool(const ushort16* __restrict__ x,
                                              const float* regW, const float* reg_b,
                                              float* out) {
    int tid = threadIdx.x;
    int p = tid & 63;
    float sx = 0.f, sy = 0.f;
    int row = blockIdx.x * 4 + (tid >> 6);
    for (; row < NN; row += gridDim.x * 4) {
        int u = x[row * 64 + p];
        f32x2 v = __builtin_amdgcn_cvt_pk_f32_fp8(u, false);
        sx += v.x; sy += v.y;
    }
    float s = sx * regW[2 * p] + sy * regW[2 * p + 1];
    for (int d = 32; d >= 1; d >>= 1) s += __shfl_down(s, d);
    __shared__ float red[4];
    if ((tid & 63) == 0) red[tid >> 6] = s;
    __syncthreads();
    if (tid == 0) {
        float t = (red[0] + red[1] + red[2] + red[3]) * (1.0f / (float)NN);
        if (blockIdx.x == 0) t += reg_b[0];
        atomicAdd(out, t);
    }
}

// ---------------- launcher ----------------

extern "C" void kernel_launch(void* const* d_in, const int* in_sizes, int n_in,
                              void* d_out, int out_size, void* d_ws, size_t ws_size,
                              hipStream_t stream) {
    const int*   z       = (const int*)d_in[0];
    const float* sd      = (const float*)d_in[1];
    const float* df      = (const float*)d_in[2];
    const float* cond    = (const float*)d_in[3];
    const float* mult    = (const float*)d_in[4];
    const int*   nt      = (const int*)d_in[5];
    const int*   ei      = (const int*)d_in[6];
    const int*   et      = (const int*)d_in[7];
    const float* z_embed = (const float*)d_in[8];
    const float* enc_W1  = (const float*)d_in[9];
    const float* enc_b1  = (const float*)d_in[10];
    const float* enc_W2  = (const float*)d_in[11];
    const float* enc_b2  = (const float*)d_in[12];
    const float* lin_W   = (const float*)d_in[13];
    const float* lin_b   = (const float*)d_in[14];
    const float* rel_W   = (const float*)d_in[15];
    const float* ln_g    = (const float*)d_in[16];
    const float* ln_b    = (const float*)d_in[17];
    const float* reg_W   = (const float*)d_in[18];
    const float* reg_b   = (const float*)d_in[19];
    float* out = (float*)d_out;

    char* p = (char*)d_ws;
    int* H          = (int*)p;      p += (size_t)PASSA_B * NBKT * 4;   // 3.2 MB
    int* btot       = (int*)p;      p += (size_t)4096 * 4;
    int* boff       = (int*)p;      p += (size_t)4096 * 4;
    int* misc       = (int*)p;      p += 16 * 4;
    int* off        = (int*)p;      p += (size_t)400384 * 4;
    int* degarr     = (int*)p;      p += (size_t)100096 * 4;
    ushort16* key16 = (ushort16*)p; p += (size_t)NE * 2;
    unsigned* hdr32 = (unsigned*)p; p += (size_t)NE * 4;
    unsigned* packed   = (unsigned*)p; p += (size_t)NE * 4;
    unsigned* packed2  = (unsigned*)p; p += (size_t)NEP * 4;
    unsigned* nodelist = (unsigned*)p; p += (size_t)NLIST2 * 4;
    ushort16* Wbh   = (ushort16*)p; p += (size_t)2 * 512 * 128 * 2;
    ushort16* Wbl   = (ushort16*)p; p += (size_t)2 * 512 * 128 * 2;
    ushort16* Weh   = (ushort16*)p; p += (size_t)65536 * 2;
    ushort16* Wel   = (ushort16*)p; p += (size_t)65536 * 2;
    unsigned char* x0 = (unsigned char*)p; p += (size_t)(NN + 1) * HD;
    unsigned char* x1 = (unsigned char*)p; p += (size_t)(NN + 1) * HD;

    hipMemsetAsync(misc, 0, 64, stream);
    hipMemsetAsync(nodelist, 0xFF, (size_t)NLIST2 * 4, stream);
    hipMemsetAsync(out, 0, 4, stream);

    k_fill_n<<<400, 256, 0, stream>>>(nt, misc, nodelist, (uint32*)x0, (uint32*)x1);
    k_hist<<<PASSA_B + WCATE_B, 256, 0, stream>>>(ei, et, H, key16, hdr32,
                                                  enc_W2, Weh, Wel);
    k_s1<<<13, 256, 0, stream>>>(H, btot);
    k_s2<<<1, 1024, 0, stream>>>(btot, boff);
    k_fill2<<<FILL_B + WCAT_B + ENC_B, 256, 0, stream>>>(
        key16, hdr32, H, boff, packed,
        nodelist, z, sd, df, cond, mult, z_embed,
        enc_W1, enc_b1, enc_b2, x0,
        rel_W, lin_W, Wbh, Wbl, Weh, Wel);
    k_sort2<<<NBKT, 256, 0, stream>>>(packed, boff, packed2, off, degarr);

    unsigned char* xin = x0; unsigned char* xo = x1;
    for (int l = 0; l < 2; l++) {
        k_fused<<<NBKT, 512, 0, stream>>>((const ushort16*)xin, packed2, off, degarr,
                                          Wbh + (size_t)l * 512 * 128,
                                          Wbl + (size_t)l * 512 * 128,
                                          lin_b + l * HD, ln_g + l * HD, ln_b + l * HD,
                                          xo);
        unsigned char* t = xin; xin = xo; xo = t;
    }
    k_pool<<<256, 256, 0, stream>>>((const ushort16*)xin, reg_W, reg_b, out);
}

// Round 14
// 458.380 us; speedup vs baseline: 5.6787x; 1.0655x over previous
//
#include <hip/hip_runtime.h>

#define NN 100000
#define NE 1600000
#define HD 128
#define IND 20
#define LNEPS 1e-5f
#define NLIST2 400000   // 4 type regions of NN
#define NBKT 3125       // dst>>5 buckets == k_fused blocks
#define PASSA_B 256
#define EDGES_PER_B 6250
#define FILL_B 256
#define WCAT_B 512
#define WCATE_B 256
#define FILLN_B 400
#define ENC_B 12500
#define NWIN 2
#define WINB 1563       // buckets per scatter window (2*1563 >= 3125)
#define ASTRIDE 260     // A-tile row stride in 32-bit words (520 bf16)
#define SORT_CAP 4096
#define PAD_PER_BKT 672 // 96 segments * up to 7 pad each
#define NEP (NE + NBKT * PAD_PER_BKT)
#define H1S 136         // enc h1 row stride in bf16 (272 B, 16B-aligned rows)

typedef unsigned int uint32;
typedef unsigned short ushort16;
typedef __attribute__((ext_vector_type(8))) short bf16x8;
typedef __attribute__((ext_vector_type(4))) float f32x4;
typedef __attribute__((ext_vector_type(2))) float f32x2;

__device__ __forceinline__ ushort16 f2bf(float f) {
    uint32 u = __float_as_uint(f);
    u += 0x7fffu + ((u >> 16) & 1u);   // round-to-nearest-even
    return (ushort16)(u >> 16);
}
__device__ __forceinline__ float bf2f1(ushort16 h) {
    return __uint_as_float(((uint32)h) << 16);
}
__device__ __forceinline__ uint32 pack2bf(float2 v) {
    return (uint32)f2bf(v.x) | ((uint32)f2bf(v.y) << 16);
}

// ---------------- pass A: bucket histogram | enc-W2 pack | node list + sentinel rows ----------
// All three roles are independent; their consumers run in LATER dispatches
// (k_fill2 / k_fused), so no same-dispatch ordering hazard (round-12 lesson).

__global__ __launch_bounds__(256) void k_hist(const int* __restrict__ ei,
                                              const int* __restrict__ et,
                                              int* __restrict__ H,
                                              ushort16* __restrict__ key16,
                                              unsigned* __restrict__ hdr32,
                                              const float* __restrict__ W2,
                                              ushort16* __restrict__ Weh,
                                              ushort16* __restrict__ Wel,
                                              const int* __restrict__ nt,
                                              int* misc, unsigned* nodelist,
                                              uint32* x0, uint32* x1) {
    __shared__ int hist[NBKT];
    int bid = blockIdx.x, tid = threadIdx.x;

    if (bid >= PASSA_B + WCATE_B) {
        // ---- node list (fixed per-type regions) + zero sentinel rows ----
        int rb = bid - PASSA_B - WCATE_B;
        int i = rb * 256 + tid;
        int st = FILLN_B * 256;
        int lane = tid & 63;
        if (rb == 0 && tid < 32) {     // zero row NN of both x buffers
            x0[(size_t)NN * 32 + tid] = 0;
            x1[(size_t)NN * 32 + tid] = 0;
        }
        for (int n = i; n < NN; n += st) {
            int t = nt[n];
#pragma unroll
            for (int tt = 0; tt < 4; tt++) {
                unsigned long long m = __ballot(t == tt);
                if (t == tt) {
                    int leader = __ffsll((unsigned long long)m) - 1;
                    int base = 0;
                    if (lane == leader) base = atomicAdd(&misc[8 + tt], (int)__popcll(m));
                    base = __shfl(base, leader);
                    int prefix = (int)__popcll(m & (((unsigned long long)1 << lane) - 1));
                    nodelist[tt * NN + base + prefix] = (unsigned)n | ((unsigned)tt << 17);
                }
            }
        }
        return;
    }
    if (bid >= PASSA_B) {
        // ---- enc W2 (per type) -> bf16 B-fragment hi/lo ----
        int idx = (bid - PASSA_B) * 256 + tid;   // exactly 4*4*8*64*8 = 65536
        int jj = idx & 7;
        int lane = (idx >> 3) & 63;
        int ntile = (idx >> 9) & 7;
        int kt = (idx >> 12) & 3;
        int t = (idx >> 14) & 3;
        int k = kt * 32 + ((lane >> 4) * 8) + jj;
        int n = ntile * 16 + (lane & 15);
        float v = W2[((size_t)t * HD + k) * HD + n];
        ushort16 hi = f2bf(v);
        Weh[idx] = hi;
        Wel[idx] = f2bf(v - bf2f1(hi));
        return;
    }

    for (int k = tid; k < NBKT; k += 256) hist[k] = 0;
    __syncthreads();
    int e0 = bid * EDGES_PER_B, e1 = e0 + EDGES_PER_B;
    for (int e = e0 + tid; e < e1; e += 256) {
        int d = ei[NE + e];
        int s = ei[e];
        int r = et[e];
        int bkt = d >> 5;
        key16[e] = (ushort16)bkt;
        hdr32[e] = (unsigned)s | ((unsigned)r << 17) | ((unsigned)(d & 31) << 19);
        atomicAdd(&hist[bkt], 1);
    }
    __syncthreads();
    for (int k = tid; k < NBKT; k += 256) H[bid * NBKT + k] = hist[k];
}

// ---------------- scans: H column-scan + bucket scan ----------------

__global__ __launch_bounds__(256) void k_s1(int* __restrict__ H, int* __restrict__ btot) {
    int bkt = blockIdx.x * 256 + threadIdx.x;
    if (bkt >= NBKT) return;
    int run = 0;
    for (int jm = 0; jm < PASSA_B; jm += 8) {
        int t0 = H[(jm + 0) * NBKT + bkt];
        int t1 = H[(jm + 1) * NBKT + bkt];
        int t2 = H[(jm + 2) * NBKT + bkt];
        int t3 = H[(jm + 3) * NBKT + bkt];
        int t4 = H[(jm + 4) * NBKT + bkt];
        int t5 = H[(jm + 5) * NBKT + bkt];
        int t6 = H[(jm + 6) * NBKT + bkt];
        int t7 = H[(jm + 7) * NBKT + bkt];
        H[(jm + 0) * NBKT + bkt] = run; run += t0;
        H[(jm + 1) * NBKT + bkt] = run; run += t1;
        H[(jm + 2) * NBKT + bkt] = run; run += t2;
        H[(jm + 3) * NBKT + bkt] = run; run += t3;
        H[(jm + 4) * NBKT + bkt] = run; run += t4;
        H[(jm + 5) * NBKT + bkt] = run; run += t5;
        H[(jm + 6) * NBKT + bkt] = run; run += t6;
        H[(jm + 7) * NBKT + bkt] = run; run += t7;
    }
    btot[bkt] = run;
}

__global__ __launch_bounds__(1024) void k_s2(const int* __restrict__ btot,
                                             int* __restrict__ boff) {
    __shared__ int s[1024];
    int t = threadIdx.x;
    int v4[4];
    int sum = 0;
#pragma unroll
    for (int i = 0; i < 4; i++) {
        int idx = t * 4 + i;
        v4[i] = (idx < NBKT) ? btot[idx] : 0;
        sum += v4[i];
    }
    s[t] = sum;
    __syncthreads();
    for (int o = 1; o < 1024; o <<= 1) {
        int tv = (t >= o) ? s[t - o] : 0;
        __syncthreads();
        s[t] += tv;
        __syncthreads();
    }
    int run = s[t] - sum;
#pragma unroll
    for (int i = 0; i < 4; i++) {
        int idx = t * 4 + i;
        if (idx < NBKT) boff[idx] = run;
        run += v4[i];
    }
    if (t == 1023) boff[NBKT] = NE;
}

// ---------------- merged: windowed scatter | layer-W pack | encoder ----------------

__global__ __launch_bounds__(256) void k_fill2(
        const ushort16* __restrict__ key16, const unsigned* __restrict__ hdr32,
        const int* __restrict__ H, const int* __restrict__ boff,
        unsigned* __restrict__ packed,
        const unsigned* __restrict__ nodelist, const int* __restrict__ z,
        const float* __restrict__ sd, const float* __restrict__ df,
        const float* __restrict__ cond, const float* __restrict__ mult,
        const float* __restrict__ z_embed,
        const float* __restrict__ W1, const float* __restrict__ b1,
        const float* __restrict__ b2,
        unsigned char* __restrict__ xout,
        const float* __restrict__ rel_W, const float* __restrict__ lin_W,
        ushort16* __restrict__ Wbh, ushort16* __restrict__ Wbl,
        const ushort16* __restrict__ Weh, const ushort16* __restrict__ Wel) {
    __shared__ __attribute__((aligned(16))) char smem[11456];
    // union: fill cur[1563] int (6252 B) | enc raw(2560)+h1b(8704)+ent(128)
    int bid = blockIdx.x;
    int tid = threadIdx.x;

    if (bid < FILL_B) {
        // ---- windowed atomic-free scatter (LDS cursors) ----
        int* cur = (int*)smem;
        int e0 = bid * EDGES_PER_B, e1 = e0 + EDGES_PER_B;
        for (int w = 0; w < NWIN; w++) {
            int lo = w * WINB;
            for (int k = tid; k < WINB; k += 256) {
                int bkt = lo + k;
                cur[k] = (bkt < NBKT) ? (boff[bkt] + H[bid * NBKT + bkt]) : 0;
            }
            __syncthreads();
            for (int e = e0 + tid; e < e1; e += 256) {
                int kb = (int)key16[e];
                unsigned d = (unsigned)(kb - lo);
                if (d < (unsigned)WINB) {
                    int p = atomicAdd(&cur[d], 1);
                    packed[p] = hdr32[e];
                }
            }
            __syncthreads();
        }
        return;
    }
    int j = bid - FILL_B;
    if (j < WCAT_B) {
        // ---- layer weights -> bf16 B-fragment hi/lo (consumed by later dispatch) ----
        int idx = j * 256 + tid;           // exactly 2*512*128
        int jj = idx & 7;
        int lane = (idx >> 3) & 63;
        int ntile = (idx >> 9) & 7;
        int kt = (idx >> 12) & 15;
        int l = (idx >> 16) & 1;
        int k = kt * 32 + ((lane >> 4) * 8) + jj;
        int n = ntile * 16 + (lane & 15);
        float v;
        if (k < 384) v = rel_W[((l * 3 + (k >> 7)) * HD + (k & 127)) * HD + n];
        else         v = lin_W[(l * HD + (k - 384)) * HD + n];
        ushort16 hi = f2bf(v);
        Wbh[idx] = hi;
        Wbl[idx] = f2bf(v - bf2f1(hi));
        return;
    }
    j -= WCAT_B;
    if (j >= ENC_B) return;

    // ---- encoder: 32 same-type nodes; layer1 VALU -> bf16 h1 -> layer2 MFMA ----
    float (*raw)[20]   = (float (*)[20])smem;
    ushort16* h1b      = (ushort16*)(smem + 2560);       // [32][H1S] bf16
    unsigned* ent      = (unsigned*)(smem + 2560 + 8704);

    int base = j * 32;
    if (tid < 32) ent[tid] = nodelist[base + tid];
    __syncthreads();
    if (ent[0] == 0xFFFFFFFFu) return;
    int type = (int)(ent[0] >> 17);

    for (int idx = tid; idx < 32 * 20; idx += 256) {
        int nl = idx / 20, f = idx - nl * 20;
        unsigned e = ent[nl];
        float v = 0.f;
        if (e != 0xFFFFFFFFu) {
            int node = (int)(e & 0x1FFFF);
            if (f < 16)      v = z_embed[z[node] * 16 + f];
            else if (f == 16) v = sd[node];
            else if (f == 17) v = df[node];
            else if (f == 18) v = cond[node];
            else              v = mult[node];
        }
        raw[nl][f] = v;
    }
    __syncthreads();

    int jf = tid & 127, n0 = (tid >> 7) * 16;
    const float* W1t = W1 + type * IND * HD;

    float acc[16];
#pragma unroll
    for (int i = 0; i < 16; i++) acc[i] = 0.f;
    for (int k = 0; k < IND; k++) {
        float w = W1t[k * HD + jf];
#pragma unroll
        for (int i = 0; i < 16; i++) acc[i] += raw[n0 + i][k] * w;
    }
    float bb = b1[type * HD + jf];
#pragma unroll
    for (int i = 0; i < 16; i++) h1b[(n0 + i) * H1S + jf] = f2bf(fmaxf(acc[i] + bb, 0.f));
    __syncthreads();

    // layer2: D[32x128] = h1[32x128] @ W2[type] via MFMA hi/lo
    int lane = tid & 63, wv = tid >> 6;
    int nt0 = 2 * wv, nt1 = 2 * wv + 1;
    f32x4 a00 = {0.f, 0.f, 0.f, 0.f}, a01 = a00, a10 = a00, a11 = a00;
    int mrow0 = lane & 15, mrow1 = 16 + (lane & 15);
    int koff = (lane >> 4) * 8;
    const bf16x8* weh = (const bf16x8*)(Weh + (size_t)type * 16384);
    const bf16x8* wel = (const bf16x8*)(Wel + (size_t)type * 16384);
    const ushort16* h1p = h1b;
#pragma unroll
    for (int kt = 0; kt < 4; kt++) {
        bf16x8 af0 = *(const bf16x8*)&h1p[mrow0 * H1S + kt * 32 + koff];
        bf16x8 af1 = *(const bf16x8*)&h1p[mrow1 * H1S + kt * 32 + koff];
        bf16x8 bh0 = weh[(kt * 8 + nt0) * 64 + lane];
        bf16x8 bh1 = weh[(kt * 8 + nt1) * 64 + lane];
        bf16x8 bl0 = wel[(kt * 8 + nt0) * 64 + lane];
        bf16x8 bl1 = wel[(kt * 8 + nt1) * 64 + lane];
        a00 = __builtin_amdgcn_mfma_f32_16x16x32_bf16(af0, bh0, a00, 0, 0, 0);
        a01 = __builtin_amdgcn_mfma_f32_16x16x32_bf16(af0, bh1, a01, 0, 0, 0);
        a10 = __builtin_amdgcn_mfma_f32_16x16x32_bf16(af1, bh0, a10, 0, 0, 0);
        a11 = __builtin_amdgcn_mfma_f32_16x16x32_bf16(af1, bh1, a11, 0, 0, 0);
        a00 = __builtin_amdgcn_mfma_f32_16x16x32_bf16(af0, bl0, a00, 0, 0, 0);
        a01 = __builtin_amdgcn_mfma_f32_16x16x32_bf16(af0, bl1, a01, 0, 0, 0);
        a10 = __builtin_amdgcn_mfma_f32_16x16x32_bf16(af1, bl0, a10, 0, 0, 0);
        a11 = __builtin_amdgcn_mfma_f32_16x16x32_bf16(af1, bl1, a11, 0, 0, 0);
    }
    int c0 = nt0 * 16 + (lane & 15), c1 = nt1 * 16 + (lane & 15);
    float b20 = b2[type * HD + c0], b21 = b2[type * HD + c1];
    int rb = (lane >> 4) * 4;
#pragma unroll
    for (int r = 0; r < 4; r++) {
        int r0 = rb + r, r1 = 16 + rb + r;
        unsigned e0v = ent[r0], e1v = ent[r1];
        if (e0v != 0xFFFFFFFFu) {
            int node = (int)(e0v & 0x1FFFF);
            int p0 = __builtin_amdgcn_cvt_pk_fp8_f32(a00[r] + b20, a00[r] + b20, 0, false);
            int p1 = __builtin_amdgcn_cvt_pk_fp8_f32(a01[r] + b21, a01[r] + b21, 0, false);
            xout[(size_t)node * HD + c0] = (unsigned char)(p0 & 0xff);
            xout[(size_t)node * HD + c1] = (unsigned char)(p1 & 0xff);
        }
        if (e1v != 0xFFFFFFFFu) {
            int node = (int)(e1v & 0x1FFFF);
            int p0 = __builtin_amdgcn_cvt_pk_fp8_f32(a10[r] + b20, a10[r] + b20, 0, false);
            int p1 = __builtin_amdgcn_cvt_pk_fp8_f32(a11[r] + b21, a11[r] + b21, 0, false);
            xout[(size_t)node * HD + c0] = (unsigned char)(p0 & 0xff);
            xout[(size_t)node * HD + c1] = (unsigned char)(p1 & 0xff);
        }
    }
}

// ---------------- in-bucket counting sort: per-(dst,rel) segments padded to 8 ----------------

__global__ __launch_bounds__(256) void k_sort2(const unsigned* __restrict__ packed,
                                               const int* __restrict__ boff,
                                               unsigned* __restrict__ packed2,
                                               int* __restrict__ off,
                                               int* __restrict__ degarr) {
    __shared__ unsigned ebuf[SORT_CAP];
    __shared__ int hs[96];
    __shared__ int cur[96];
    __shared__ int segp[97];   // padded segment starts (96) + end
    int b = blockIdx.x;
    int tid = threadIdx.x;
    int base = boff[b];
    int tot = boff[b + 1] - base;
    if (tot > SORT_CAP) tot = SORT_CAP;   // statistically impossible (mean 512, sigma 23)
    int pb = base + PAD_PER_BKT * b;

    if (tid < 96) hs[tid] = 0;
    for (int e = tid; e < tot; e += 256) ebuf[e] = packed[base + e];
    __syncthreads();
    for (int e = tid; e < tot; e += 256) {
        unsigned h = ebuf[e];
        int key = (int)(h >> 19) * 3 + (int)((h >> 17) & 3);
        atomicAdd(&hs[key], 1);
    }
    __syncthreads();
    if (tid == 0) {
        int run = 0;
        for (int k = 0; k < 96; k++) {
            segp[k] = run;
            run += (hs[k] + 7) & ~7;
        }
        segp[96] = run;
    }
    __syncthreads();
    if (tid < 96) {
        cur[tid] = segp[tid];
        off[((b * 32 + tid / 3) << 2) + (tid % 3)] = pb + segp[tid];
    }
    if (tid >= 96 && tid < 128) {
        int n = tid - 96;
        off[((b * 32 + n) << 2) + 3] = pb + segp[3 * n + 3];
        degarr[b * 32 + n] = hs[3 * n] + hs[3 * n + 1] + hs[3 * n + 2];
    }
    __syncthreads();
    for (int e = tid; e < tot; e += 256) {
        unsigned h = ebuf[e];
        int key = (int)(h >> 19) * 3 + (int)((h >> 17) & 3);
        int p = atomicAdd(&cur[key], 1);
        packed2[pb + p] = h & 0x1FFFF;
    }
    __syncthreads();
    if (tid < 96) {   // sentinel-fill each segment's tail
        int e0 = segp[tid] + hs[tid];
        int e1 = segp[tid + 1];
        for (int q = e0; q < e1; q++) packed2[pb + q] = NN;
    }
}

// ---------------- fused layer: register agg (pure-rel 8-groups) -> MFMA -> LN ----------------
// 512 threads = 8 waves; wave w aggregates 4 nodes. Every 8-group lies inside
// one rel segment (segments padded to 8 with zero-row sentinels) -> scalar
// 3-way branch picks the accumulator; adds unconditional. 32-bit addressing.
// Epilogue: regW==nullptr -> fp8 x write; else fused mean-pool + regressor
// (one atomicAdd per block; x write skipped — dead for the final layer).

#define ADD8(AX, AY)                                                         \
    AX += v0.x + v1.x; AY += v0.y + v1.y;                                    \
    AX += v2.x + v3.x; AY += v2.y + v3.y;                                    \
    AX += v4.x + v5.x; AY += v4.y + v5.y;                                    \
    AX += v6.x + v7.x; AY += v6.y + v7.y;

__global__ __launch_bounds__(512, 6) void k_fused(
        const ushort16* __restrict__ x,        // fp8 e4m3, 2 features per ushort, row stride 64
        const unsigned* __restrict__ packed,   // src-only, (dst,rel)-sorted, seg-8-padded
        const int* __restrict__ off, const int* __restrict__ degarr,
        const ushort16* __restrict__ Wbh, const ushort16* __restrict__ Wbl,
        const float* __restrict__ lb, const float* __restrict__ g,
        const float* __restrict__ bta, unsigned char* __restrict__ xout,
        const float* __restrict__ regW, const float* __restrict__ reg_b,
        float* __restrict__ out) {
    __shared__ uint32 Alds[32 * ASTRIDE];   // bf16 A-tile [32][520]; aliased as hlds [32][132] f32
    __shared__ float stat[32][2];
    __shared__ float red[8];
    int tid = threadIdx.x;
    int lane = tid & 63;
    int wv = tid >> 6;                     // 0..7
    int nb = blockIdx.x * 32;

    int bv = off[((nb + wv * 4) << 2) + lane];        // 16 boundaries for 4 nodes
    int dgv = degarr[nb + wv * 4 + (lane & 3)];       // real degrees

    // ---- phase A ----
#pragma unroll
    for (int i = 0; i < 4; i++) {
        int node = nb + wv * 4 + i;
        int bb0 = __builtin_amdgcn_readlane(bv, 4 * i);
        int bb1 = __builtin_amdgcn_readlane(bv, 4 * i + 1);
        int bb2 = __builtin_amdgcn_readlane(bv, 4 * i + 2);
        int bb3 = __builtin_amdgcn_readlane(bv, 4 * i + 3);
        int rdeg = __builtin_amdgcn_readlane(dgv, i);
        float id = 1.0f / (float)(rdeg > 0 ? rdeg : 1);
        int us = x[node * 64 + lane];                 // self row (early issue)
        float a0x = 0.f, a0y = 0.f, a1x = 0.f, a1y = 0.f, a2x = 0.f, a2y = 0.f;
        for (int e = bb0; e < bb3; e += 8) {
            unsigned q0 = packed[e];
            unsigned q1 = packed[e + 1];
            unsigned q2 = packed[e + 2];
            unsigned q3 = packed[e + 3];
            unsigned q4 = packed[e + 4];
            unsigned q5 = packed[e + 5];
            unsigned q6 = packed[e + 6];
            unsigned q7 = packed[e + 7];
            int u0 = x[(int)q0 * 64 + lane];
            int u1 = x[(int)q1 * 64 + lane];
            int u2 = x[(int)q2 * 64 + lane];
            int u3 = x[(int)q3 * 64 + lane];
            int u4 = x[(int)q4 * 64 + lane];
            int u5 = x[(int)q5 * 64 + lane];
            int u6 = x[(int)q6 * 64 + lane];
            int u7 = x[(int)q7 * 64 + lane];
            f32x2 v0 = __builtin_amdgcn_cvt_pk_f32_fp8(u0, false);
            f32x2 v1 = __builtin_amdgcn_cvt_pk_f32_fp8(u1, false);
            f32x2 v2 = __builtin_amdgcn_cvt_pk_f32_fp8(u2, false);
            f32x2 v3 = __builtin_amdgcn_cvt_pk_f32_fp8(u3, false);
            f32x2 v4 = __builtin_amdgcn_cvt_pk_f32_fp8(u4, false);
            f32x2 v5 = __builtin_amdgcn_cvt_pk_f32_fp8(u5, false);
            f32x2 v6 = __builtin_amdgcn_cvt_pk_f32_fp8(u6, false);
            f32x2 v7 = __builtin_amdgcn_cvt_pk_f32_fp8(u7, false);
            if (e < bb1)      { ADD8(a0x, a0y) }
            else if (e < bb2) { ADD8(a1x, a1y) }
            else              { ADD8(a2x, a2y) }
        }
        uint32* ar = Alds + (wv * 4 + i) * ASTRIDE;
        float2 s0 = {a0x * id, a0y * id};
        float2 s1 = {a1x * id, a1y * id};
        float2 s2 = {a2x * id, a2y * id};
        f32x2 vs = __builtin_amdgcn_cvt_pk_f32_fp8(us, false);
        float2 s3 = {vs.x, vs.y};
        ar[lane]       = pack2bf(s0);
        ar[64 + lane]  = pack2bf(s1);
        ar[128 + lane] = pack2bf(s2);
        ar[192 + lane] = pack2bf(s3);
    }
    __syncthreads();

    // ---- phase B: MFMA GEMM (W = Whi + Wlo); wave w: n-tile w, m-tiles {0,1} ----
    f32x4 acc00 = {0.f, 0.f, 0.f, 0.f}, acc10 = acc00;
    int mrow0 = (lane & 15);
    int mrow1 = 16 + (lane & 15);
    int q4 = (lane >> 4) * 4;
    const bf16x8* wbh = (const bf16x8*)Wbh;
    const bf16x8* wbl = (const bf16x8*)Wbl;

#pragma unroll 4
    for (int kt = 0; kt < 16; kt++) {
        bf16x8 af0 = *(const bf16x8*)&Alds[mrow0 * ASTRIDE + kt * 16 + q4];
        bf16x8 af1 = *(const bf16x8*)&Alds[mrow1 * ASTRIDE + kt * 16 + q4];
        bf16x8 bh0 = wbh[(kt * 8 + wv) * 64 + lane];
        bf16x8 bl0 = wbl[(kt * 8 + wv) * 64 + lane];
        acc00 = __builtin_amdgcn_mfma_f32_16x16x32_bf16(af0, bh0, acc00, 0, 0, 0);
        acc10 = __builtin_amdgcn_mfma_f32_16x16x32_bf16(af1, bh0, acc10, 0, 0, 0);
        acc00 = __builtin_amdgcn_mfma_f32_16x16x32_bf16(af0, bl0, acc00, 0, 0, 0);
        acc10 = __builtin_amdgcn_mfma_f32_16x16x32_bf16(af1, bl0, acc10, 0, 0, 0);
    }
    __syncthreads();   // A-tile reads done; alias as hlds

    // ---- bias into LDS for LN stats ----
    float* hlds = (float*)Alds;            // [32][132]
    int n0 = wv * 16 + (lane & 15);
    float bj0 = lb[n0];
    int rbase = (lane >> 4) * 4;
#pragma unroll
    for (int r = 0; r < 4; r++) {
        hlds[(rbase + r) * 132 + n0]      = acc00[r] + bj0;
        hlds[(16 + rbase + r) * 132 + n0] = acc10[r] + bj0;
    }
    __syncthreads();

    {
        int node = tid >> 4, l16 = tid & 15;
        float s = 0.f, ss = 0.f;
#pragma unroll
        for (int i = 0; i < 8; i++) {
            float v = hlds[node * 132 + l16 + 16 * i];
            s += v; ss += v * v;
        }
        for (int d = 8; d >= 1; d >>= 1) {
            s += __shfl_down(s, d, 16);
            ss += __shfl_down(ss, d, 16);
        }
        if (l16 == 0) {
            float mu = s * (1.f / 128.f);
            float var = ss * (1.f / 128.f) - mu * mu;
            stat[node][0] = mu;
            stat[node][1] = rsqrtf(var + LNEPS);
        }
    }
    __syncthreads();

    // ---- LN epilogue: fp8 repack+store OR fused pool+regressor ----
    {
        int node = tid >> 4, q16 = tid & 15;
        float mu = stat[node][0], rs = stat[node][1];
        const float* hr = hlds + node * 132 + q16 * 8;
        float vv[8];
#pragma unroll
        for (int k = 0; k < 8; k++) {
            int f = q16 * 8 + k;
            vv[k] = (hr[k] - mu) * rs * g[f] + bta[f];
        }
        if (regW == nullptr) {
            int w[2];
#pragma unroll
            for (int p = 0; p < 2; p++) {
                int pk = __builtin_amdgcn_cvt_pk_fp8_f32(vv[p * 4 + 0], vv[p * 4 + 1], 0, false);
                pk = __builtin_amdgcn_cvt_pk_fp8_f32(vv[p * 4 + 2], vv[p * 4 + 3], pk, true);
                w[p] = pk;
            }
            *(int2*)(xout + (size_t)(nb + node) * 128 + q16 * 8) = make_int2(w[0], w[1]);
        } else {
            float s = 0.f;
#pragma unroll
            for (int k = 0; k < 8; k++) s += vv[k] * regW[q16 * 8 + k];
            for (int d = 32; d >= 1; d >>= 1) s += __shfl_down(s, d);
            if (lane == 0) red[wv] = s;
            __syncthreads();
            if (tid == 0) {
                float t = (red[0] + red[1] + red[2] + red[3] +
                           red[4] + red[5] + red[6] + red[7]) * (1.0f / (float)NN);
                if (blockIdx.x == 0) t += reg_b[0];
                atomicAdd(out, t);
            }
        }
    }
}

// ---------------- launcher ----------------

extern "C" void kernel_launch(void* const* d_in, const int* in_sizes, int n_in,
                              void* d_out, int out_size, void* d_ws, size_t ws_size,
                              hipStream_t stream) {
    const int*   z       = (const int*)d_in[0];
    const float* sd      = (const float*)d_in[1];
    const float* df      = (const float*)d_in[2];
    const float* cond    = (const float*)d_in[3];
    const float* mult    = (const float*)d_in[4];
    const int*   nt      = (const int*)d_in[5];
    const int*   ei      = (const int*)d_in[6];
    const int*   et      = (const int*)d_in[7];
    const float* z_embed = (const float*)d_in[8];
    const float* enc_W1  = (const float*)d_in[9];
    const float* enc_b1  = (const float*)d_in[10];
    const float* enc_W2  = (const float*)d_in[11];
    const float* enc_b2  = (const float*)d_in[12];
    const float* lin_W   = (const float*)d_in[13];
    const float* lin_b   = (const float*)d_in[14];
    const float* rel_W   = (const float*)d_in[15];
    const float* ln_g    = (const float*)d_in[16];
    const float* ln_b    = (const float*)d_in[17];
    const float* reg_W   = (const float*)d_in[18];
    const float* reg_b   = (const float*)d_in[19];
    float* out = (float*)d_out;

    char* p = (char*)d_ws;
    int* H          = (int*)p;      p += (size_t)PASSA_B * NBKT * 4;   // 3.2 MB
    int* btot       = (int*)p;      p += (size_t)4096 * 4;
    int* boff       = (int*)p;      p += (size_t)4096 * 4;
    int* misc       = (int*)p;      p += 16 * 4;
    int* off        = (int*)p;      p += (size_t)400384 * 4;
    int* degarr     = (int*)p;      p += (size_t)100096 * 4;
    ushort16* key16 = (ushort16*)p; p += (size_t)NE * 2;
    unsigned* hdr32 = (unsigned*)p; p += (size_t)NE * 4;
    unsigned* packed   = (unsigned*)p; p += (size_t)NE * 4;
    unsigned* packed2  = (unsigned*)p; p += (size_t)NEP * 4;
    unsigned* nodelist = (unsigned*)p; p += (size_t)NLIST2 * 4;
    ushort16* Wbh   = (ushort16*)p; p += (size_t)2 * 512 * 128 * 2;
    ushort16* Wbl   = (ushort16*)p; p += (size_t)2 * 512 * 128 * 2;
    ushort16* Weh   = (ushort16*)p; p += (size_t)65536 * 2;
    ushort16* Wel   = (ushort16*)p; p += (size_t)65536 * 2;
    unsigned char* x0 = (unsigned char*)p; p += (size_t)(NN + 1) * HD;
    unsigned char* x1 = (unsigned char*)p; p += (size_t)(NN + 1) * HD;

    hipMemsetAsync(misc, 0, 64, stream);
    hipMemsetAsync(nodelist, 0xFF, (size_t)NLIST2 * 4, stream);
    hipMemsetAsync(out, 0, 4, stream);

    k_hist<<<PASSA_B + WCATE_B + FILLN_B, 256, 0, stream>>>(
        ei, et, H, key16, hdr32, enc_W2, Weh, Wel,
        nt, misc, nodelist, (uint32*)x0, (uint32*)x1);
    k_s1<<<13, 256, 0, stream>>>(H, btot);
    k_s2<<<1, 1024, 0, stream>>>(btot, boff);
    k_fill2<<<FILL_B + WCAT_B + ENC_B, 256, 0, stream>>>(
        key16, hdr32, H, boff, packed,
        nodelist, z, sd, df, cond, mult, z_embed,
        enc_W1, enc_b1, enc_b2, x0,
        rel_W, lin_W, Wbh, Wbl, Weh, Wel);
    k_sort2<<<NBKT, 256, 0, stream>>>(packed, boff, packed2, off, degarr);

    // layer 0: x0 -> x1 (fp8 write)
    k_fused<<<NBKT, 512, 0, stream>>>((const ushort16*)x0, packed2, off, degarr,
                                      Wbh, Wbl,
                                      lin_b, ln_g, ln_b,
                                      x1, nullptr, nullptr, out);
    // layer 1: x1 -> fused mean-pool + regressor (x write skipped)
    k_fused<<<NBKT, 512, 0, stream>>>((const ushort16*)x1, packed2, off, degarr,
                                      Wbh + (size_t)512 * 128, Wbl + (size_t)512 * 128,
                                      lin_b + HD, ln_g + HD, ln_b + HD,
                                      x0, reg_W, reg_b, out);
}

// Round 15
// 448.007 us; speedup vs baseline: 5.8101x; 1.0232x over previous
//
#include <hip/hip_runtime.h>

#define NN 100000
#define NE 1600000
#define HD 128
#define IND 20
#define LNEPS 1e-5f
#define NLIST2 400000   // 4 type regions of NN
#define NBKT 3125       // dst>>5 buckets == k_fused blocks
#define PASSA_B 256
#define EDGES_PER_B 6250
#define FILL_B 256
#define WCAT_B 512
#define WCATE_B 256
#define FILLN_B 400
#define ENC_B 12500
#define NWIN 2
#define WINB 1563       // buckets per scatter window (2*1563 >= 3125)
#define ASTRIDE 260     // A-tile row stride in 32-bit words (520 bf16)
#define SORT_CAP 4096
#define PAD_PER_BKT 672 // 96 segments * up to 7 pad each
#define NEP (NE + NBKT * PAD_PER_BKT)
#define H1S 136         // enc h1 row stride in bf16 (272 B, 16B-aligned rows)

typedef unsigned int uint32;
typedef unsigned short ushort16;
typedef __attribute__((ext_vector_type(8))) short bf16x8;
typedef __attribute__((ext_vector_type(4))) float f32x4;
typedef __attribute__((ext_vector_type(2))) float f32x2;

__device__ __forceinline__ ushort16 f2bf(float f) {
    uint32 u = __float_as_uint(f);
    u += 0x7fffu + ((u >> 16) & 1u);   // round-to-nearest-even
    return (ushort16)(u >> 16);
}
__device__ __forceinline__ float bf2f1(ushort16 h) {
    return __uint_as_float(((uint32)h) << 16);
}
__device__ __forceinline__ uint32 pack2bf(float2 v) {
    return (uint32)f2bf(v.x) | ((uint32)f2bf(v.y) << 16);
}

// ---------------- pass A: bucket histogram | enc-W2 pack | node list + sentinel rows ----------
// All three roles are independent; their consumers run in LATER dispatches
// (k_fill2 / k_fused), so no same-dispatch ordering hazard (round-12 lesson).

__global__ __launch_bounds__(256) void k_hist(const int* __restrict__ ei,
                                              const int* __restrict__ et,
                                              int* __restrict__ H,
                                              ushort16* __restrict__ key16,
                                              unsigned* __restrict__ hdr32,
                                              const float* __restrict__ W2,
                                              ushort16* __restrict__ Weh,
                                              ushort16* __restrict__ Wel,
                                              const int* __restrict__ nt,
                                              int* misc, unsigned* nodelist,
                                              uint32* x0, uint32* x1) {
    __shared__ int hist[NBKT];
    int bid = blockIdx.x, tid = threadIdx.x;

    if (bid >= PASSA_B + WCATE_B) {
        // ---- node list (fixed per-type regions) + zero sentinel rows ----
        int rb = bid - PASSA_B - WCATE_B;
        int i = rb * 256 + tid;
        int st = FILLN_B * 256;
        int lane = tid & 63;
        if (rb == 0 && tid < 32) {     // zero row NN of both x buffers
            x0[(size_t)NN * 32 + tid] = 0;
            x1[(size_t)NN * 32 + tid] = 0;
        }
        for (int n = i; n < NN; n += st) {
            int t = nt[n];
#pragma unroll
            for (int tt = 0; tt < 4; tt++) {
                unsigned long long m = __ballot(t == tt);
                if (t == tt) {
                    int leader = __ffsll((unsigned long long)m) - 1;
                    int base = 0;
                    if (lane == leader) base = atomicAdd(&misc[8 + tt], (int)__popcll(m));
                    base = __shfl(base, leader);
                    int prefix = (int)__popcll(m & (((unsigned long long)1 << lane) - 1));
                    nodelist[tt * NN + base + prefix] = (unsigned)n | ((unsigned)tt << 17);
                }
            }
        }
        return;
    }
    if (bid >= PASSA_B) {
        // ---- enc W2 (per type) -> bf16 B-fragment hi/lo ----
        int idx = (bid - PASSA_B) * 256 + tid;   // exactly 4*4*8*64*8 = 65536
        int jj = idx & 7;
        int lane = (idx >> 3) & 63;
        int ntile = (idx >> 9) & 7;
        int kt = (idx >> 12) & 3;
        int t = (idx >> 14) & 3;
        int k = kt * 32 + ((lane >> 4) * 8) + jj;
        int n = ntile * 16 + (lane & 15);
        float v = W2[((size_t)t * HD + k) * HD + n];
        ushort16 hi = f2bf(v);
        Weh[idx] = hi;
        Wel[idx] = f2bf(v - bf2f1(hi));
        return;
    }

    for (int k = tid; k < NBKT; k += 256) hist[k] = 0;
    __syncthreads();
    int e0 = bid * EDGES_PER_B, e1 = e0 + EDGES_PER_B;
    for (int e = e0 + tid; e < e1; e += 256) {
        int d = ei[NE + e];
        int s = ei[e];
        int r = et[e];
        int bkt = d >> 5;
        key16[e] = (ushort16)bkt;
        hdr32[e] = (unsigned)s | ((unsigned)r << 17) | ((unsigned)(d & 31) << 19);
        atomicAdd(&hist[bkt], 1);
    }
    __syncthreads();
    for (int k = tid; k < NBKT; k += 256) H[bid * NBKT + k] = hist[k];
}

// ---------------- scans: H column-scan + bucket scan ----------------

__global__ __launch_bounds__(256) void k_s1(int* __restrict__ H, int* __restrict__ btot) {
    int bkt = blockIdx.x * 256 + threadIdx.x;
    if (bkt >= NBKT) return;
    int run = 0;
    for (int jm = 0; jm < PASSA_B; jm += 8) {
        int t0 = H[(jm + 0) * NBKT + bkt];
        int t1 = H[(jm + 1) * NBKT + bkt];
        int t2 = H[(jm + 2) * NBKT + bkt];
        int t3 = H[(jm + 3) * NBKT + bkt];
        int t4 = H[(jm + 4) * NBKT + bkt];
        int t5 = H[(jm + 5) * NBKT + bkt];
        int t6 = H[(jm + 6) * NBKT + bkt];
        int t7 = H[(jm + 7) * NBKT + bkt];
        H[(jm + 0) * NBKT + bkt] = run; run += t0;
        H[(jm + 1) * NBKT + bkt] = run; run += t1;
        H[(jm + 2) * NBKT + bkt] = run; run += t2;
        H[(jm + 3) * NBKT + bkt] = run; run += t3;
        H[(jm + 4) * NBKT + bkt] = run; run += t4;
        H[(jm + 5) * NBKT + bkt] = run; run += t5;
        H[(jm + 6) * NBKT + bkt] = run; run += t6;
        H[(jm + 7) * NBKT + bkt] = run; run += t7;
    }
    btot[bkt] = run;
}

__global__ __launch_bounds__(1024) void k_s2(const int* __restrict__ btot,
                                             int* __restrict__ boff) {
    __shared__ int s[1024];
    int t = threadIdx.x;
    int v4[4];
    int sum = 0;
#pragma unroll
    for (int i = 0; i < 4; i++) {
        int idx = t * 4 + i;
        v4[i] = (idx < NBKT) ? btot[idx] : 0;
        sum += v4[i];
    }
    s[t] = sum;
    __syncthreads();
    for (int o = 1; o < 1024; o <<= 1) {
        int tv = (t >= o) ? s[t - o] : 0;
        __syncthreads();
        s[t] += tv;
        __syncthreads();
    }
    int run = s[t] - sum;
#pragma unroll
    for (int i = 0; i < 4; i++) {
        int idx = t * 4 + i;
        if (idx < NBKT) boff[idx] = run;
        run += v4[i];
    }
    if (t == 1023) boff[NBKT] = NE;
}

// ---------------- merged: windowed scatter | layer-W pack | encoder ----------------

__global__ __launch_bounds__(256) void k_fill2(
        const ushort16* __restrict__ key16, const unsigned* __restrict__ hdr32,
        const int* __restrict__ H, const int* __restrict__ boff,
        unsigned* __restrict__ packed,
        const unsigned* __restrict__ nodelist, const int* __restrict__ z,
        const float* __restrict__ sd, const float* __restrict__ df,
        const float* __restrict__ cond, const float* __restrict__ mult,
        const float* __restrict__ z_embed,
        const float* __restrict__ W1, const float* __restrict__ b1,
        const float* __restrict__ b2,
        unsigned char* __restrict__ xout,
        const float* __restrict__ rel_W, const float* __restrict__ lin_W,
        ushort16* __restrict__ Wbh, ushort16* __restrict__ Wbl,
        const ushort16* __restrict__ Weh, const ushort16* __restrict__ Wel) {
    __shared__ __attribute__((aligned(16))) char smem[11456];
    // union: fill cur[1563] int (6252 B) | enc raw(2560)+h1b(8704)+ent(128)
    int bid = blockIdx.x;
    int tid = threadIdx.x;

    if (bid < FILL_B) {
        // ---- windowed atomic-free scatter (LDS cursors) ----
        int* cur = (int*)smem;
        int e0 = bid * EDGES_PER_B, e1 = e0 + EDGES_PER_B;
        for (int w = 0; w < NWIN; w++) {
            int lo = w * WINB;
            for (int k = tid; k < WINB; k += 256) {
                int bkt = lo + k;
                cur[k] = (bkt < NBKT) ? (boff[bkt] + H[bid * NBKT + bkt]) : 0;
            }
            __syncthreads();
            for (int e = e0 + tid; e < e1; e += 256) {
                int kb = (int)key16[e];
                unsigned d = (unsigned)(kb - lo);
                if (d < (unsigned)WINB) {
                    int p = atomicAdd(&cur[d], 1);
                    packed[p] = hdr32[e];
                }
            }
            __syncthreads();
        }
        return;
    }
    int j = bid - FILL_B;
    if (j < WCAT_B) {
        // ---- layer weights -> bf16 B-fragment hi/lo (consumed by later dispatch) ----
        int idx = j * 256 + tid;           // exactly 2*512*128
        int jj = idx & 7;
        int lane = (idx >> 3) & 63;
        int ntile = (idx >> 9) & 7;
        int kt = (idx >> 12) & 15;
        int l = (idx >> 16) & 1;
        int k = kt * 32 + ((lane >> 4) * 8) + jj;
        int n = ntile * 16 + (lane & 15);
        float v;
        if (k < 384) v = rel_W[((l * 3 + (k >> 7)) * HD + (k & 127)) * HD + n];
        else         v = lin_W[(l * HD + (k - 384)) * HD + n];
        ushort16 hi = f2bf(v);
        Wbh[idx] = hi;
        Wbl[idx] = f2bf(v - bf2f1(hi));
        return;
    }
    j -= WCAT_B;
    if (j >= ENC_B) return;

    // ---- encoder: 32 same-type nodes; layer1 VALU -> bf16 h1 -> layer2 MFMA ----
    float (*raw)[20]   = (float (*)[20])smem;
    ushort16* h1b      = (ushort16*)(smem + 2560);       // [32][H1S] bf16
    unsigned* ent      = (unsigned*)(smem + 2560 + 8704);

    int base = j * 32;
    if (tid < 32) ent[tid] = nodelist[base + tid];
    __syncthreads();
    if (ent[0] == 0xFFFFFFFFu) return;
    int type = (int)(ent[0] >> 17);

    for (int idx = tid; idx < 32 * 20; idx += 256) {
        int nl = idx / 20, f = idx - nl * 20;
        unsigned e = ent[nl];
        float v = 0.f;
        if (e != 0xFFFFFFFFu) {
            int node = (int)(e & 0x1FFFF);
            if (f < 16)      v = z_embed[z[node] * 16 + f];
            else if (f == 16) v = sd[node];
            else if (f == 17) v = df[node];
            else if (f == 18) v = cond[node];
            else              v = mult[node];
        }
        raw[nl][f] = v;
    }
    __syncthreads();

    int jf = tid & 127, n0 = (tid >> 7) * 16;
    const float* W1t = W1 + type * IND * HD;

    float acc[16];
#pragma unroll
    for (int i = 0; i < 16; i++) acc[i] = 0.f;
    for (int k = 0; k < IND; k++) {
        float w = W1t[k * HD + jf];
#pragma unroll
        for (int i = 0; i < 16; i++) acc[i] += raw[n0 + i][k] * w;
    }
    float bb = b1[type * HD + jf];
#pragma unroll
    for (int i = 0; i < 16; i++) h1b[(n0 + i) * H1S + jf] = f2bf(fmaxf(acc[i] + bb, 0.f));
    __syncthreads();

    // layer2: D[32x128] = h1[32x128] @ W2[type] via MFMA hi/lo
    int lane = tid & 63, wv = tid >> 6;
    int nt0 = 2 * wv, nt1 = 2 * wv + 1;
    f32x4 a00 = {0.f, 0.f, 0.f, 0.f}, a01 = a00, a10 = a00, a11 = a00;
    int mrow0 = lane & 15, mrow1 = 16 + (lane & 15);
    int koff = (lane >> 4) * 8;
    const bf16x8* weh = (const bf16x8*)(Weh + (size_t)type * 16384);
    const bf16x8* wel = (const bf16x8*)(Wel + (size_t)type * 16384);
    const ushort16* h1p = h1b;
#pragma unroll
    for (int kt = 0; kt < 4; kt++) {
        bf16x8 af0 = *(const bf16x8*)&h1p[mrow0 * H1S + kt * 32 + koff];
        bf16x8 af1 = *(const bf16x8*)&h1p[mrow1 * H1S + kt * 32 + koff];
        bf16x8 bh0 = weh[(kt * 8 + nt0) * 64 + lane];
        bf16x8 bh1 = weh[(kt * 8 + nt1) * 64 + lane];
        bf16x8 bl0 = wel[(kt * 8 + nt0) * 64 + lane];
        bf16x8 bl1 = wel[(kt * 8 + nt1) * 64 + lane];
        a00 = __builtin_amdgcn_mfma_f32_16x16x32_bf16(af0, bh0, a00, 0, 0, 0);
        a01 = __builtin_amdgcn_mfma_f32_16x16x32_bf16(af0, bh1, a01, 0, 0, 0);
        a10 = __builtin_amdgcn_mfma_f32_16x16x32_bf16(af1, bh0, a10, 0, 0, 0);
        a11 = __builtin_amdgcn_mfma_f32_16x16x32_bf16(af1, bh1, a11, 0, 0, 0);
        a00 = __builtin_amdgcn_mfma_f32_16x16x32_bf16(af0, bl0, a00, 0, 0, 0);
        a01 = __builtin_amdgcn_mfma_f32_16x16x32_bf16(af0, bl1, a01, 0, 0, 0);
        a10 = __builtin_amdgcn_mfma_f32_16x16x32_bf16(af1, bl0, a10, 0, 0, 0);
        a11 = __builtin_amdgcn_mfma_f32_16x16x32_bf16(af1, bl1, a11, 0, 0, 0);
    }
    int c0 = nt0 * 16 + (lane & 15), c1 = nt1 * 16 + (lane & 15);
    float b20 = b2[type * HD + c0], b21 = b2[type * HD + c1];
    int rb = (lane >> 4) * 4;
#pragma unroll
    for (int r = 0; r < 4; r++) {
        int r0 = rb + r, r1 = 16 + rb + r;
        unsigned e0v = ent[r0], e1v = ent[r1];
        if (e0v != 0xFFFFFFFFu) {
            int node = (int)(e0v & 0x1FFFF);
            int p0 = __builtin_amdgcn_cvt_pk_fp8_f32(a00[r] + b20, a00[r] + b20, 0, false);
            int p1 = __builtin_amdgcn_cvt_pk_fp8_f32(a01[r] + b21, a01[r] + b21, 0, false);
            xout[(size_t)node * HD + c0] = (unsigned char)(p0 & 0xff);
            xout[(size_t)node * HD + c1] = (unsigned char)(p1 & 0xff);
        }
        if (e1v != 0xFFFFFFFFu) {
            int node = (int)(e1v & 0x1FFFF);
            int p0 = __builtin_amdgcn_cvt_pk_fp8_f32(a10[r] + b20, a10[r] + b20, 0, false);
            int p1 = __builtin_amdgcn_cvt_pk_fp8_f32(a11[r] + b21, a11[r] + b21, 0, false);
            xout[(size_t)node * HD + c0] = (unsigned char)(p0 & 0xff);
            xout[(size_t)node * HD + c1] = (unsigned char)(p1 & 0xff);
        }
    }
}

// ---------------- in-bucket counting sort: per-(dst,rel) segments padded to 8 ----------------

__global__ __launch_bounds__(256) void k_sort2(const unsigned* __restrict__ packed,
                                               const int* __restrict__ boff,
                                               unsigned* __restrict__ packed2,
                                               int* __restrict__ off,
                                               int* __restrict__ degarr) {
    __shared__ unsigned ebuf[SORT_CAP];
    __shared__ int hs[96];
    __shared__ int cur[96];
    __shared__ int segp[97];   // padded segment starts (96) + end
    int b = blockIdx.x;
    int tid = threadIdx.x;
    int base = boff[b];
    int tot = boff[b + 1] - base;
    if (tot > SORT_CAP) tot = SORT_CAP;   // statistically impossible (mean 512, sigma 23)
    int pb = base + PAD_PER_BKT * b;

    if (tid < 96) hs[tid] = 0;
    for (int e = tid; e < tot; e += 256) ebuf[e] = packed[base + e];
    __syncthreads();
    for (int e = tid; e < tot; e += 256) {
        unsigned h = ebuf[e];
        int key = (int)(h >> 19) * 3 + (int)((h >> 17) & 3);
        atomicAdd(&hs[key], 1);
    }
    __syncthreads();
    if (tid == 0) {
        int run = 0;
        for (int k = 0; k < 96; k++) {
            segp[k] = run;
            run += (hs[k] + 7) & ~7;
        }
        segp[96] = run;
    }
    __syncthreads();
    if (tid < 96) {
        cur[tid] = segp[tid];
        off[((b * 32 + tid / 3) << 2) + (tid % 3)] = pb + segp[tid];
    }
    if (tid >= 96 && tid < 128) {
        int n = tid - 96;
        off[((b * 32 + n) << 2) + 3] = pb + segp[3 * n + 3];
        degarr[b * 32 + n] = hs[3 * n] + hs[3 * n + 1] + hs[3 * n + 2];
    }
    __syncthreads();
    for (int e = tid; e < tot; e += 256) {
        unsigned h = ebuf[e];
        int key = (int)(h >> 19) * 3 + (int)((h >> 17) & 3);
        int p = atomicAdd(&cur[key], 1);
        packed2[pb + p] = h & 0x1FFFF;
    }
    __syncthreads();
    if (tid < 96) {   // sentinel-fill each segment's tail
        int e0 = segp[tid] + hs[tid];
        int e1 = segp[tid + 1];
        for (int q = e0; q < e1; q++) packed2[pb + q] = NN;
    }
}

// ---------------- fused layer: register agg (pure-rel 8-groups) -> MFMA -> LN ----------------
// 512 threads = 8 waves; wave w aggregates 4 nodes. Every 8-group lies inside
// one rel segment (segments padded to 8 with zero-row sentinels) -> scalar
// 3-way branch picks the accumulator; adds unconditional. 32-bit addressing.
// Epilogue: regW==nullptr -> fp8 x write; else fused mean-pool dot written as
// an UNCONTENDED per-block partial (G12 — 3125 same-address atomics cost ~11us).

#define ADD8(AX, AY)                                                         \
    AX += v0.x + v1.x; AY += v0.y + v1.y;                                    \
    AX += v2.x + v3.x; AY += v2.y + v3.y;                                    \
    AX += v4.x + v5.x; AY += v4.y + v5.y;                                    \
    AX += v6.x + v7.x; AY += v6.y + v7.y;

__global__ __launch_bounds__(512, 6) void k_fused(
        const ushort16* __restrict__ x,        // fp8 e4m3, 2 features per ushort, row stride 64
        const unsigned* __restrict__ packed,   // src-only, (dst,rel)-sorted, seg-8-padded
        const int* __restrict__ off, const int* __restrict__ degarr,
        const ushort16* __restrict__ Wbh, const ushort16* __restrict__ Wbl,
        const float* __restrict__ lb, const float* __restrict__ g,
        const float* __restrict__ bta, unsigned char* __restrict__ xout,
        const float* __restrict__ regW, float* __restrict__ partials) {
    __shared__ uint32 Alds[32 * ASTRIDE];   // bf16 A-tile [32][520]; aliased as hlds [32][132] f32
    __shared__ float stat[32][2];
    __shared__ float red[8];
    int tid = threadIdx.x;
    int lane = tid & 63;
    int wv = tid >> 6;                     // 0..7
    int nb = blockIdx.x * 32;

    int bv = off[((nb + wv * 4) << 2) + lane];        // 16 boundaries for 4 nodes
    int dgv = degarr[nb + wv * 4 + (lane & 3)];       // real degrees

    // ---- phase A ----
#pragma unroll
    for (int i = 0; i < 4; i++) {
        int node = nb + wv * 4 + i;
        int bb0 = __builtin_amdgcn_readlane(bv, 4 * i);
        int bb1 = __builtin_amdgcn_readlane(bv, 4 * i + 1);
        int bb2 = __builtin_amdgcn_readlane(bv, 4 * i + 2);
        int bb3 = __builtin_amdgcn_readlane(bv, 4 * i + 3);
        int rdeg = __builtin_amdgcn_readlane(dgv, i);
        float id = 1.0f / (float)(rdeg > 0 ? rdeg : 1);
        int us = x[node * 64 + lane];                 // self row (early issue)
        float a0x = 0.f, a0y = 0.f, a1x = 0.f, a1y = 0.f, a2x = 0.f, a2y = 0.f;
        for (int e = bb0; e < bb3; e += 8) {
            unsigned q0 = packed[e];
            unsigned q1 = packed[e + 1];
            unsigned q2 = packed[e + 2];
            unsigned q3 = packed[e + 3];
            unsigned q4 = packed[e + 4];
            unsigned q5 = packed[e + 5];
            unsigned q6 = packed[e + 6];
            unsigned q7 = packed[e + 7];
            int u0 = x[(int)q0 * 64 + lane];
            int u1 = x[(int)q1 * 64 + lane];
            int u2 = x[(int)q2 * 64 + lane];
            int u3 = x[(int)q3 * 64 + lane];
            int u4 = x[(int)q4 * 64 + lane];
            int u5 = x[(int)q5 * 64 + lane];
            int u6 = x[(int)q6 * 64 + lane];
            int u7 = x[(int)q7 * 64 + lane];
            f32x2 v0 = __builtin_amdgcn_cvt_pk_f32_fp8(u0, false);
            f32x2 v1 = __builtin_amdgcn_cvt_pk_f32_fp8(u1, false);
            f32x2 v2 = __builtin_amdgcn_cvt_pk_f32_fp8(u2, false);
            f32x2 v3 = __builtin_amdgcn_cvt_pk_f32_fp8(u3, false);
            f32x2 v4 = __builtin_amdgcn_cvt_pk_f32_fp8(u4, false);
            f32x2 v5 = __builtin_amdgcn_cvt_pk_f32_fp8(u5, false);
            f32x2 v6 = __builtin_amdgcn_cvt_pk_f32_fp8(u6, false);
            f32x2 v7 = __builtin_amdgcn_cvt_pk_f32_fp8(u7, false);
            if (e < bb1)      { ADD8(a0x, a0y) }
            else if (e < bb2) { ADD8(a1x, a1y) }
            else              { ADD8(a2x, a2y) }
        }
        uint32* ar = Alds + (wv * 4 + i) * ASTRIDE;
        float2 s0 = {a0x * id, a0y * id};
        float2 s1 = {a1x * id, a1y * id};
        float2 s2 = {a2x * id, a2y * id};
        f32x2 vs = __builtin_amdgcn_cvt_pk_f32_fp8(us, false);
        float2 s3 = {vs.x, vs.y};
        ar[lane]       = pack2bf(s0);
        ar[64 + lane]  = pack2bf(s1);
        ar[128 + lane] = pack2bf(s2);
        ar[192 + lane] = pack2bf(s3);
    }
    __syncthreads();

    // ---- phase B: MFMA GEMM (W = Whi + Wlo); wave w: n-tile w, m-tiles {0,1} ----
    f32x4 acc00 = {0.f, 0.f, 0.f, 0.f}, acc10 = acc00;
    int mrow0 = (lane & 15);
    int mrow1 = 16 + (lane & 15);
    int q4 = (lane >> 4) * 4;
    const bf16x8* wbh = (const bf16x8*)Wbh;
    const bf16x8* wbl = (const bf16x8*)Wbl;

#pragma unroll 4
    for (int kt = 0; kt < 16; kt++) {
        bf16x8 af0 = *(const bf16x8*)&Alds[mrow0 * ASTRIDE + kt * 16 + q4];
        bf16x8 af1 = *(const bf16x8*)&Alds[mrow1 * ASTRIDE + kt * 16 + q4];
        bf16x8 bh0 = wbh[(kt * 8 + wv) * 64 + lane];
        bf16x8 bl0 = wbl[(kt * 8 + wv) * 64 + lane];
        acc00 = __builtin_amdgcn_mfma_f32_16x16x32_bf16(af0, bh0, acc00, 0, 0, 0);
        acc10 = __builtin_amdgcn_mfma_f32_16x16x32_bf16(af1, bh0, acc10, 0, 0, 0);
        acc00 = __builtin_amdgcn_mfma_f32_16x16x32_bf16(af0, bl0, acc00, 0, 0, 0);
        acc10 = __builtin_amdgcn_mfma_f32_16x16x32_bf16(af1, bl0, acc10, 0, 0, 0);
    }
    __syncthreads();   // A-tile reads done; alias as hlds

    // ---- bias into LDS for LN stats ----
    float* hlds = (float*)Alds;            // [32][132]
    int n0 = wv * 16 + (lane & 15);
    float bj0 = lb[n0];
    int rbase = (lane >> 4) * 4;
#pragma unroll
    for (int r = 0; r < 4; r++) {
        hlds[(rbase + r) * 132 + n0]      = acc00[r] + bj0;
        hlds[(16 + rbase + r) * 132 + n0] = acc10[r] + bj0;
    }
    __syncthreads();

    {
        int node = tid >> 4, l16 = tid & 15;
        float s = 0.f, ss = 0.f;
#pragma unroll
        for (int i = 0; i < 8; i++) {
            float v = hlds[node * 132 + l16 + 16 * i];
            s += v; ss += v * v;
        }
        for (int d = 8; d >= 1; d >>= 1) {
            s += __shfl_down(s, d, 16);
            ss += __shfl_down(ss, d, 16);
        }
        if (l16 == 0) {
            float mu = s * (1.f / 128.f);
            float var = ss * (1.f / 128.f) - mu * mu;
            stat[node][0] = mu;
            stat[node][1] = rsqrtf(var + LNEPS);
        }
    }
    __syncthreads();

    // ---- LN epilogue: fp8 repack+store OR fused pool partial ----
    {
        int node = tid >> 4, q16 = tid & 15;
        float mu = stat[node][0], rs = stat[node][1];
        const float* hr = hlds + node * 132 + q16 * 8;
        float vv[8];
#pragma unroll
        for (int k = 0; k < 8; k++) {
            int f = q16 * 8 + k;
            vv[k] = (hr[k] - mu) * rs * g[f] + bta[f];
        }
        if (regW == nullptr) {
            int w[2];
#pragma unroll
            for (int p = 0; p < 2; p++) {
                int pk = __builtin_amdgcn_cvt_pk_fp8_f32(vv[p * 4 + 0], vv[p * 4 + 1], 0, false);
                pk = __builtin_amdgcn_cvt_pk_fp8_f32(vv[p * 4 + 2], vv[p * 4 + 3], pk, true);
                w[p] = pk;
            }
            *(int2*)(xout + (size_t)(nb + node) * 128 + q16 * 8) = make_int2(w[0], w[1]);
        } else {
            float s = 0.f;
#pragma unroll
            for (int k = 0; k < 8; k++) s += vv[k] * regW[q16 * 8 + k];
            for (int d = 32; d >= 1; d >>= 1) s += __shfl_down(s, d);
            if (lane == 0) red[wv] = s;
            __syncthreads();
            if (tid == 0) {
                partials[blockIdx.x] = red[0] + red[1] + red[2] + red[3] +
                                       red[4] + red[5] + red[6] + red[7];
            }
        }
    }
}

// ---------------- final reduction: 3125 partials -> scalar out ----------------

__global__ __launch_bounds__(1024) void k_red(const float* __restrict__ partials,
                                              const float* __restrict__ reg_b,
                                              float* __restrict__ out) {
    __shared__ float s[16];
    int tid = threadIdx.x;
    float v = 0.f;
    for (int i = tid; i < NBKT; i += 1024) v += partials[i];
    for (int d = 32; d >= 1; d >>= 1) v += __shfl_down(v, d);
    if ((tid & 63) == 0) s[tid >> 6] = v;
    __syncthreads();
    if (tid == 0) {
        float t = 0.f;
#pragma unroll
        for (int i = 0; i < 16; i++) t += s[i];
        out[0] = t * (1.0f / (float)NN) + reg_b[0];
    }
}

// ---------------- launcher ----------------

extern "C" void kernel_launch(void* const* d_in, const int* in_sizes, int n_in,
                              void* d_out, int out_size, void* d_ws, size_t ws_size,
                              hipStream_t stream) {
    const int*   z       = (const int*)d_in[0];
    const float* sd      = (const float*)d_in[1];
    const float* df      = (const float*)d_in[2];
    const float* cond    = (const float*)d_in[3];
    const float* mult    = (const float*)d_in[4];
    const int*   nt      = (const int*)d_in[5];
    const int*   ei      = (const int*)d_in[6];
    const int*   et      = (const int*)d_in[7];
    const float* z_embed = (const float*)d_in[8];
    const float* enc_W1  = (const float*)d_in[9];
    const float* enc_b1  = (const float*)d_in[10];
    const float* enc_W2  = (const float*)d_in[11];
    const float* enc_b2  = (const float*)d_in[12];
    const float* lin_W   = (const float*)d_in[13];
    const float* lin_b   = (const float*)d_in[14];
    const float* rel_W   = (const float*)d_in[15];
    const float* ln_g    = (const float*)d_in[16];
    const float* ln_b    = (const float*)d_in[17];
    const float* reg_W   = (const float*)d_in[18];
    const float* reg_b   = (const float*)d_in[19];
    float* out = (float*)d_out;

    char* p = (char*)d_ws;
    int* H          = (int*)p;      p += (size_t)PASSA_B * NBKT * 4;   // 3.2 MB
    int* btot       = (int*)p;      p += (size_t)4096 * 4;
    int* boff       = (int*)p;      p += (size_t)4096 * 4;
    int* misc       = (int*)p;      p += 16 * 4;
    float* partials = (float*)p;    p += (size_t)4096 * 4;
    int* off        = (int*)p;      p += (size_t)400384 * 4;
    int* degarr     = (int*)p;      p += (size_t)100096 * 4;
    ushort16* key16 = (ushort16*)p; p += (size_t)NE * 2;
    unsigned* hdr32 = (unsigned*)p; p += (size_t)NE * 4;
    unsigned* packed   = (unsigned*)p; p += (size_t)NE * 4;
    unsigned* packed2  = (unsigned*)p; p += (size_t)NEP * 4;
    unsigned* nodelist = (unsigned*)p; p += (size_t)NLIST2 * 4;
    ushort16* Wbh   = (ushort16*)p; p += (size_t)2 * 512 * 128 * 2;
    ushort16* Wbl   = (ushort16*)p; p += (size_t)2 * 512 * 128 * 2;
    ushort16* Weh   = (ushort16*)p; p += (size_t)65536 * 2;
    ushort16* Wel   = (ushort16*)p; p += (size_t)65536 * 2;
    unsigned char* x0 = (unsigned char*)p; p += (size_t)(NN + 1) * HD;
    unsigned char* x1 = (unsigned char*)p; p += (size_t)(NN + 1) * HD;

    hipMemsetAsync(misc, 0, 64, stream);
    hipMemsetAsync(nodelist, 0xFF, (size_t)NLIST2 * 4, stream);

    k_hist<<<PASSA_B + WCATE_B + FILLN_B, 256, 0, stream>>>(
        ei, et, H, key16, hdr32, enc_W2, Weh, Wel,
        nt, misc, nodelist, (uint32*)x0, (uint32*)x1);
    k_s1<<<13, 256, 0, stream>>>(H, btot);
    k_s2<<<1, 1024, 0, stream>>>(btot, boff);
    k_fill2<<<FILL_B + WCAT_B + ENC_B, 256, 0, stream>>>(
        key16, hdr32, H, boff, packed,
        nodelist, z, sd, df, cond, mult, z_embed,
        enc_W1, enc_b1, enc_b2, x0,
        rel_W, lin_W, Wbh, Wbl, Weh, Wel);
    k_sort2<<<NBKT, 256, 0, stream>>>(packed, boff, packed2, off, degarr);

    // layer 0: x0 -> x1 (fp8 write)
    k_fused<<<NBKT, 512, 0, stream>>>((const ushort16*)x0, packed2, off, degarr,
                                      Wbh, Wbl,
                                      lin_b, ln_g, ln_b,
                                      x1, nullptr, partials);
    // layer 1: x1 -> per-block pool partials (x write skipped)
    k_fused<<<NBKT, 512, 0, stream>>>((const ushort16*)x1, packed2, off, degarr,
                                      Wbh + (size_t)512 * 128, Wbl + (size_t)512 * 128,
                                      lin_b + HD, ln_g + HD, ln_b + HD,
                                      x0, reg_W, partials);
    k_red<<<1, 1024, 0, stream>>>(partials, reg_b, out);
}